// Round 3
// baseline (723.628 us; speedup 1.0000x reference)
//
#include <hip/hip_runtime.h>

#define BTOK 32768   // B*H*W tokens
#define CC 256
#define CC2 512
#define NBATCH 8

typedef __bf16 bf16x8 __attribute__((ext_vector_type(8)));
typedef float f32x4 __attribute__((ext_vector_type(4)));
typedef unsigned short u16x8 __attribute__((ext_vector_type(8)));
typedef unsigned short u16x4 __attribute__((ext_vector_type(4)));

__device__ __forceinline__ float b2f(unsigned short u) {
    return __uint_as_float(((unsigned)u) << 16);
}
__device__ __forceinline__ unsigned short f2b(float f) {
    unsigned x = __float_as_uint(f);
    return (unsigned short)((x + 0x7fffu + ((x >> 16) & 1u)) >> 16);
}
__device__ __forceinline__ float wredsum(float v) {
#pragma unroll
    for (int m = 1; m < 64; m <<= 1) v += __shfl_xor(v, m);
    return v;
}

// ---------------- dtype probe: 1 = bf16 inputs, 0 = f32 inputs ----------------
__global__ __launch_bounds__(256) void probe_kernel(
    const unsigned short* __restrict__ x, int* __restrict__ flag)
{
    int t = threadIdx.x;
    int c = 0;
    for (int i = t; i < 1024; i += 256) {
        unsigned e = (x[i] >> 7) & 0xFFu;
        c += (e >= 110u && e <= 135u) ? 1 : 0;
    }
#pragma unroll
    for (int m = 1; m < 64; m <<= 1) c += __shfl_xor(c, m);
    __shared__ int acc[4];
    if ((t & 63) == 0) acc[t >> 6] = c;
    __syncthreads();
    if (t == 0) *flag = ((acc[0] + acc[1] + acc[2] + acc[3]) >= 896) ? 1 : 0;
}

// ---------------- convert all params to bf16 in ws ----------------
__global__ __launch_bounds__(256) void cvt_params_kernel(
    const int* __restrict__ flagp,
    const void* p0, const void* p1, const void* p2, const void* p3, const void* p4,
    const void* p5, const void* p6, const void* p7, const void* p8, const void* p9,
    const void* p10, const void* p11, const void* p12, const void* p13, const void* p14,
    const void* p15, const void* p16, const void* p17, const void* p18, const void* p19,
    unsigned short* __restrict__ dst)
{
    bool isb = (*flagp != 0);
    long g = (long)blockIdx.x * 256 + threadIdx.x;
    long str = (long)gridDim.x * 256;
#define CVT(src, off, n)                                                        \
    for (long i = g; i < (long)(n); i += str)                                   \
        dst[(off) + i] = isb ? ((const unsigned short*)(src))[i]                \
                             : f2b(((const float*)(src))[i]);
    CVT(p0, 0, 256)          // n1g
    CVT(p1, 256, 256)        // n1b
    CVT(p2, 512, 65536)      // linw
    CVT(p3, 66048, 256)      // linb
    CVT(p4, 66304, 65536)    // repw
    CVT(p5, 131840, 256)     // repb
    CVT(p6, 132096, 256)     // ang
    CVT(p7, 132352, 256)     // anb
    CVT(p8, 132608, 256)     // g2
    CVT(p9, 132864, 256)     // b2v
    CVT(p10, 133120, 131072) // fc1w
    CVT(p11, 264192, 512)    // fc1b
    CVT(p12, 264704, 4608)   // dww
    CVT(p13, 269312, 512)    // dwb
    CVT(p14, 269824, 512)    // fn1g
    CVT(p15, 270336, 512)    // fn1b
    CVT(p16, 270848, 131072) // fc2w
    CVT(p17, 401920, 256)    // fc2b
    CVT(p18, 402176, 256)    // fn3g
    CVT(p19, 402432, 256)    // fn3b
#undef CVT
}

// ---------------- LN of x1 and x2 (shared norm1 params), dtype-aware ----------------
__global__ __launch_bounds__(256) void ln_dual_kernel(
    const void* __restrict__ x1, const void* __restrict__ x2,
    const unsigned short* __restrict__ g, const unsigned short* __restrict__ b,
    unsigned short* __restrict__ out, const int* __restrict__ flagp)
{
    bool isb = (*flagp != 0);
    int wid = threadIdx.x >> 6, l = threadIdx.x & 63;
    long row = (long)blockIdx.x * 4 + wid;   // 0 .. 2*BTOK-1
    const void* xsel = (row < BTOK) ? x1 : x2;
    long r = (row < BTOK) ? row : (row - BTOK);
    float f[4];
    if (isb) {
        u16x4 v = *reinterpret_cast<const u16x4*>((const unsigned short*)xsel + r * CC + l * 4);
#pragma unroll
        for (int j = 0; j < 4; j++) f[j] = b2f(v[j]);
    } else {
        f32x4 v = *reinterpret_cast<const f32x4*>((const float*)xsel + r * CC + l * 4);
#pragma unroll
        for (int j = 0; j < 4; j++) f[j] = v[j];
    }
    float mean = wredsum(f[0] + f[1] + f[2] + f[3]) * (1.f / CC);
    float d[4], sq = 0.f;
#pragma unroll
    for (int j = 0; j < 4; j++) { d[j] = f[j] - mean; sq += d[j] * d[j]; }
    float rs = rsqrtf(wredsum(sq) * (1.f / CC) + 1e-5f);
    u16x4 gv = *reinterpret_cast<const u16x4*>(g + l * 4);
    u16x4 bv = *reinterpret_cast<const u16x4*>(b + l * 4);
    u16x4 o;
#pragma unroll
    for (int j = 0; j < 4; j++) o[j] = f2b(d[j] * rs * b2f(gv[j]) + b2f(bv[j]));
    *reinterpret_cast<u16x4*>(out + row * CC + l * 4) = o;
}

// ---------------- GEMM: out[t][o] = sum_k A[t][k]*W[o][k] + bias[o] ----------------
template<int K>
__global__ __launch_bounds__(256) void gemm_bt_kernel(
    const unsigned short* __restrict__ A, const unsigned short* __restrict__ Wt,
    const unsigned short* __restrict__ bias, unsigned short* __restrict__ out,
    int T, int O)
{
    int l = threadIdx.x & 63;
    int wg = blockIdx.x * 4 + (threadIdx.x >> 6);
    int ntn = O >> 5;
    int tm = (wg / ntn) << 5;
    int tn = (wg % ntn) << 5;
    int rr = l & 15;
    int ko = (l >> 4) << 3;
    const unsigned short* a0 = A + (long)(tm + rr) * K + ko;
    const unsigned short* b0 = Wt + (long)(tn + rr) * K + ko;
    f32x4 acc00 = {0.f, 0.f, 0.f, 0.f};
    f32x4 acc01 = acc00, acc10 = acc00, acc11 = acc00;
    for (int k = 0; k < K; k += 32) {
        bf16x8 af0 = *reinterpret_cast<const bf16x8*>(a0 + k);
        bf16x8 af1 = *reinterpret_cast<const bf16x8*>(a0 + 16 * K + k);
        bf16x8 bv0 = *reinterpret_cast<const bf16x8*>(b0 + k);
        bf16x8 bv1 = *reinterpret_cast<const bf16x8*>(b0 + 16 * K + k);
        acc00 = __builtin_amdgcn_mfma_f32_16x16x32_bf16(af0, bv0, acc00, 0, 0, 0);
        acc01 = __builtin_amdgcn_mfma_f32_16x16x32_bf16(af0, bv1, acc01, 0, 0, 0);
        acc10 = __builtin_amdgcn_mfma_f32_16x16x32_bf16(af1, bv0, acc10, 0, 0, 0);
        acc11 = __builtin_amdgcn_mfma_f32_16x16x32_bf16(af1, bv1, acc11, 0, 0, 0);
    }
    int orow = (l >> 4) << 2;
    int ocol = l & 15;
    float bi0 = b2f(bias[tn + ocol]);
    float bi1 = b2f(bias[tn + 16 + ocol]);
#pragma unroll
    for (int j = 0; j < 4; j++) {
        out[(long)(tm + orow + j) * O + tn + ocol]           = f2b(acc00[j] + bi0);
        out[(long)(tm + orow + j) * O + tn + 16 + ocol]      = f2b(acc01[j] + bi1);
        out[(long)(tm + 16 + orow + j) * O + tn + ocol]      = f2b(acc10[j] + bi0);
        out[(long)(tm + 16 + orow + j) * O + tn + 16 + ocol] = f2b(acc11[j] + bi1);
    }
}

// ---------------- column (token-axis) softmax stats for k ----------------
__global__ __launch_bounds__(256) void colstats_kernel(
    const unsigned short* __restrict__ n2, float* __restrict__ kmax, float* __restrict__ ksum)
{
    int b = blockIdx.x >> 3;
    int c0 = (blockIdx.x & 7) << 5;
    int c = c0 + (threadIdx.x & 31);
    int r0 = threadIdx.x >> 5;
    const unsigned short* base = n2 + ((long)b * 4096) * CC + c;
    float m = -3.0e38f, s = 0.f;
    for (int n = r0; n < 4096; n += 8) {
        float x = b2f(base[(long)n * CC]);
        if (x > m) { s = s * __expf(m - x) + 1.f; m = x; }
        else s += __expf(x - m);
    }
    __shared__ float lm[8][33], ls[8][33];
    lm[r0][threadIdx.x & 31] = m;
    ls[r0][threadIdx.x & 31] = s;
    __syncthreads();
    if (threadIdx.x < 32) {
        float M = lm[0][threadIdx.x], S = ls[0][threadIdx.x];
        for (int i = 1; i < 8; i++) {
            float mi = lm[i][threadIdx.x], si = ls[i][threadIdx.x];
            if (mi > M) { S = S * __expf(M - mi) + si; M = mi; }
            else S += si * __expf(mi - M);
        }
        kmax[b * CC + c0 + threadIdx.x] = M;
        ksum[b * CC + c0 + threadIdx.x] = S;
    }
}

// ---------------- context[b,h,d,v] = sum_n softmaxk[d,n] * v[v,n] ----------------
__global__ __launch_bounds__(256) void ctx_kernel(
    const unsigned short* __restrict__ n2, const float* __restrict__ kmax,
    const float* __restrict__ ksum, float* __restrict__ ctx)
{
    int b = blockIdx.x >> 3, hd = blockIdx.x & 7;
    int t = threadIdx.x;
    __shared__ float ld[32][33], eld[32][33];
    int d = t >> 3;
    int v0 = (t & 7) << 2;
    int ln_ = t >> 3;
    int lc = (t & 7) << 2;
    float kmx4[4];
#pragma unroll
    for (int j = 0; j < 4; j++) kmx4[j] = kmax[b * CC + hd * 32 + lc + j];
    f32x4 acc = {0.f, 0.f, 0.f, 0.f};
    const unsigned short* base = n2 + ((long)b * 4096) * CC + hd * 32;
    for (int n0 = 0; n0 < 4096; n0 += 32) {
        u16x4 rv = *reinterpret_cast<const u16x4*>(base + (long)(n0 + ln_) * CC + lc);
#pragma unroll
        for (int j = 0; j < 4; j++) {
            float x = b2f(rv[j]);
            ld[ln_][lc + j] = x;
            eld[ln_][lc + j] = __expf(x - kmx4[j]);
        }
        __syncthreads();
#pragma unroll 4
        for (int nn = 0; nn < 32; nn++) {
            float e = eld[nn][d];
#pragma unroll
            for (int j = 0; j < 4; j++) acc[j] += e * ld[nn][v0 + j];
        }
        __syncthreads();
    }
    float inv = 1.f / ksum[b * CC + hd * 32 + d];
#pragma unroll
    for (int j = 0; j < 4; j++)
        ctx[(((long)b * 8 + hd) * 32 + d) * 32 + v0 + j] = acc[j] * inv;
}

// ---------------- q-softmax + att = ctx^T q, per token ----------------
__global__ __launch_bounds__(256) void att_kernel(
    const unsigned short* __restrict__ n1, const float* __restrict__ ctx,
    unsigned short* __restrict__ attv)
{
    __shared__ float cl[32 * 256];
    __shared__ float ql[4][264];
    int b = blockIdx.x >> 6, grp = blockIdx.x & 63;
    int t = threadIdx.x, wid = t >> 6, l = t & 63;
    const float* cb = ctx + (long)b * 8192;
    for (int i = 0; i < 32; i++) {
        int gidx = t + (i << 8);
        int hd_ = gidx >> 10, dd = (gidx >> 5) & 31, vv = gidx & 31;
        cl[dd * 256 + hd_ * 32 + vv] = cb[gidx];
    }
    __syncthreads();
    int hd = l >> 3;
    long tokbase = (long)b * 4096 + grp * 64 + wid * 16;
    const f32x4* c4 = reinterpret_cast<const f32x4*>(cl);
    for (int it = 0; it < 16; it++) {
        long tok = tokbase + it;
        u16x4 rv = *reinterpret_cast<const u16x4*>(n1 + tok * CC + l * 4);
        float x[4];
#pragma unroll
        for (int j = 0; j < 4; j++) x[j] = b2f(rv[j]);
        float mx = fmaxf(fmaxf(x[0], x[1]), fmaxf(x[2], x[3]));
        mx = fmaxf(mx, __shfl_xor(mx, 1));
        mx = fmaxf(mx, __shfl_xor(mx, 2));
        mx = fmaxf(mx, __shfl_xor(mx, 4));
        float e[4], s = 0.f;
#pragma unroll
        for (int j = 0; j < 4; j++) { e[j] = __expf(x[j] - mx); s += e[j]; }
        s += __shfl_xor(s, 1);
        s += __shfl_xor(s, 2);
        s += __shfl_xor(s, 4);
        float inv = 1.f / s;
#pragma unroll
        for (int j = 0; j < 4; j++) ql[wid][hd * 33 + ((l & 7) << 2) + j] = e[j] * inv;
        __syncthreads();
        f32x4 o = {0.f, 0.f, 0.f, 0.f};
#pragma unroll 8
        for (int dd = 0; dd < 32; dd++) {
            float qd = ql[wid][hd * 33 + dd];
            o += qd * c4[dd * 64 + l];
        }
        __syncthreads();
        u16x4 ov;
#pragma unroll
        for (int j = 0; j < 4; j++) ov[j] = f2b(o[j]);
        *reinterpret_cast<u16x4*>(attv + tok * CC + l * 4) = ov;
    }
}

// ---------------- attn_out = LN(rep); y = LN(attn_out + x1), dtype-aware x1 ----------------
__global__ __launch_bounds__(256) void y_kernel(
    const unsigned short* __restrict__ rep, const void* __restrict__ x1,
    const unsigned short* __restrict__ ag, const unsigned short* __restrict__ ab,
    const unsigned short* __restrict__ g2, const unsigned short* __restrict__ b2v,
    unsigned short* __restrict__ yout, const int* __restrict__ flagp)
{
    bool isb = (*flagp != 0);
    int wid = threadIdx.x >> 6, l = threadIdx.x & 63;
    long tok = (long)blockIdx.x * 4 + wid;
    long base = tok * CC + l * 4;
    u16x4 rv = *reinterpret_cast<const u16x4*>(rep + base);
    float f[4];
#pragma unroll
    for (int j = 0; j < 4; j++) f[j] = b2f(rv[j]);
    float mean = wredsum(f[0] + f[1] + f[2] + f[3]) * (1.f / CC);
    float d[4], sq = 0.f;
#pragma unroll
    for (int j = 0; j < 4; j++) { d[j] = f[j] - mean; sq += d[j] * d[j]; }
    float rs = rsqrtf(wredsum(sq) * (1.f / CC) + 1e-5f);
    u16x4 gv = *reinterpret_cast<const u16x4*>(ag + l * 4);
    u16x4 bv = *reinterpret_cast<const u16x4*>(ab + l * 4);
    float xv[4];
    if (isb) {
        u16x4 x4v = *reinterpret_cast<const u16x4*>((const unsigned short*)x1 + base);
#pragma unroll
        for (int j = 0; j < 4; j++) xv[j] = b2f(x4v[j]);
    } else {
        f32x4 x4v = *reinterpret_cast<const f32x4*>((const float*)x1 + base);
#pragma unroll
        for (int j = 0; j < 4; j++) xv[j] = x4v[j];
    }
    float tt[4];
#pragma unroll
    for (int j = 0; j < 4; j++) tt[j] = d[j] * rs * b2f(gv[j]) + b2f(bv[j]) + xv[j];
    float mean2 = wredsum(tt[0] + tt[1] + tt[2] + tt[3]) * (1.f / CC);
    float d2[4], sq2 = 0.f;
#pragma unroll
    for (int j = 0; j < 4; j++) { d2[j] = tt[j] - mean2; sq2 += d2[j] * d2[j]; }
    float rs2 = rsqrtf(wredsum(sq2) * (1.f / CC) + 1e-5f);
    u16x4 gv2 = *reinterpret_cast<const u16x4*>(g2 + l * 4);
    u16x4 bv2 = *reinterpret_cast<const u16x4*>(b2v + l * 4);
    u16x4 o;
#pragma unroll
    for (int j = 0; j < 4; j++) o[j] = f2b(d2[j] * rs2 * b2f(gv2[j]) + b2f(bv2[j]));
    *reinterpret_cast<u16x4*>(yout + base) = o;
}

// ---------------- depthwise 3x3 conv + LN + exact GELU ----------------
__global__ __launch_bounds__(256) void dw_kernel(
    const unsigned short* __restrict__ h1, const unsigned short* __restrict__ dww,
    const unsigned short* __restrict__ dwb, const unsigned short* __restrict__ g,
    const unsigned short* __restrict__ bb, unsigned short* __restrict__ ax)
{
    int wid = threadIdx.x >> 6, l = threadIdx.x & 63;
    int pix = blockIdx.x * 4 + wid;
    int b = pix >> 12, rem = pix & 4095, py = rem >> 6, px = rem & 63;
    int c0 = l * 8;
    float acc[8];
#pragma unroll
    for (int j = 0; j < 8; j++) acc[j] = b2f(dwb[c0 + j]);
#pragma unroll
    for (int ky = 0; ky < 3; ky++) {
        int ys = py + ky - 1;
        if ((unsigned)ys >= 64u) continue;
#pragma unroll
        for (int kx = 0; kx < 3; kx++) {
            int xs = px + kx - 1;
            if ((unsigned)xs >= 64u) continue;
            u16x8 pv = *reinterpret_cast<const u16x8*>(
                h1 + ((long)(b << 12) + (ys << 6) + xs) * CC2 + c0);
#pragma unroll
            for (int j = 0; j < 8; j++)
                acc[j] += b2f(pv[j]) * b2f(dww[(c0 + j) * 9 + ky * 3 + kx]);
        }
    }
    float s = 0.f;
#pragma unroll
    for (int j = 0; j < 8; j++) s += acc[j];
    float mean = wredsum(s) * (1.f / CC2);
    float d[8], sq = 0.f;
#pragma unroll
    for (int j = 0; j < 8; j++) { d[j] = acc[j] - mean; sq += d[j] * d[j]; }
    float rs = rsqrtf(wredsum(sq) * (1.f / CC2) + 1e-5f);
    u16x8 gv = *reinterpret_cast<const u16x8*>(g + c0);
    u16x8 bv = *reinterpret_cast<const u16x8*>(bb + c0);
    u16x8 o;
#pragma unroll
    for (int j = 0; j < 8; j++) {
        float nv = d[j] * rs * b2f(gv[j]) + b2f(bv[j]);
        o[j] = f2b(0.5f * nv * (1.f + erff(nv * 0.70710678118654752f)));
    }
    *reinterpret_cast<u16x8*>(ax + (long)pix * CC2 + c0) = o;
}

// ---------------- final: out = LN(fout + y), dtype-aware output ----------------
__global__ __launch_bounds__(256) void final_kernel(
    const unsigned short* __restrict__ fout, const unsigned short* __restrict__ y,
    const unsigned short* __restrict__ g, const unsigned short* __restrict__ bb,
    void* __restrict__ out, const int* __restrict__ flagp)
{
    bool isb = (*flagp != 0);
    int wid = threadIdx.x >> 6, l = threadIdx.x & 63;
    long tok = (long)blockIdx.x * 4 + wid;
    long base = tok * CC + l * 4;
    u16x4 fv = *reinterpret_cast<const u16x4*>(fout + base);
    u16x4 yv = *reinterpret_cast<const u16x4*>(y + base);
    float f[4];
#pragma unroll
    for (int j = 0; j < 4; j++) f[j] = b2f(fv[j]) + b2f(yv[j]);
    float mean = wredsum(f[0] + f[1] + f[2] + f[3]) * (1.f / CC);
    float d[4], sq = 0.f;
#pragma unroll
    for (int j = 0; j < 4; j++) { d[j] = f[j] - mean; sq += d[j] * d[j]; }
    float rs = rsqrtf(wredsum(sq) * (1.f / CC) + 1e-5f);
    u16x4 gv = *reinterpret_cast<const u16x4*>(g + l * 4);
    u16x4 bv = *reinterpret_cast<const u16x4*>(bb + l * 4);
    float r[4];
#pragma unroll
    for (int j = 0; j < 4; j++) r[j] = d[j] * rs * b2f(gv[j]) + b2f(bv[j]);
    if (isb) {
        u16x4 o;
#pragma unroll
        for (int j = 0; j < 4; j++) o[j] = f2b(r[j]);
        *reinterpret_cast<u16x4*>((unsigned short*)out + base) = o;
    } else {
        f32x4 o;
#pragma unroll
        for (int j = 0; j < 4; j++) o[j] = r[j];
        *reinterpret_cast<f32x4*>((float*)out + base) = o;
    }
}

extern "C" void kernel_launch(void* const* d_in, const int* in_sizes, int n_in,
                              void* d_out, int out_size, void* d_ws, size_t ws_size,
                              hipStream_t stream)
{
    char* w = (char*)d_ws;
    const size_t S1B = (size_t)BTOK * CC * 2;   // 16.78 MB
    const size_t STATSB = (size_t)(2 * NBATCH * CC + NBATCH * 8 * 32 * 32) * 4;
    const size_t PARAMS_ELEMS = 402688;
    const size_t need = 6 * S1B + STATSB + 64 + PARAMS_ELEMS * 2;
    if (ws_size < need) return;

    unsigned short* ln12 = (unsigned short*)w;
    unsigned short* n12  = (unsigned short*)(w + 2 * S1B);
    unsigned short* nn1  = n12;
    unsigned short* nn2  = n12 + (size_t)BTOK * CC;
    unsigned short* attv = ln12;
    unsigned short* rep  = ln12 + (size_t)BTOK * CC;
    unsigned short* ybuf = nn1;
    unsigned short* fout = nn2;
    unsigned short* h1   = ln12;
    unsigned short* axb  = (unsigned short*)(w + 4 * S1B);
    float* kmax = (float*)(w + 6 * S1B);
    float* ksum = kmax + NBATCH * CC;
    float* ctxb = ksum + NBATCH * CC;
    int*   flag = (int*)(w + 6 * S1B + STATSB);
    unsigned short* pb = (unsigned short*)(w + 6 * S1B + STATSB + 64);

    // bf16 param block offsets
    unsigned short* n1g  = pb + 0;
    unsigned short* n1b  = pb + 256;
    unsigned short* linw = pb + 512;
    unsigned short* linb = pb + 66048;
    unsigned short* repw = pb + 66304;
    unsigned short* repb = pb + 131840;
    unsigned short* ang  = pb + 132096;
    unsigned short* anb  = pb + 132352;
    unsigned short* g2   = pb + 132608;
    unsigned short* b2v  = pb + 132864;
    unsigned short* fc1w = pb + 133120;
    unsigned short* fc1b = pb + 264192;
    unsigned short* dww  = pb + 264704;
    unsigned short* dwb  = pb + 269312;
    unsigned short* fn1g = pb + 269824;
    unsigned short* fn1b = pb + 270336;
    unsigned short* fc2w = pb + 270848;
    unsigned short* fc2b = pb + 401920;
    unsigned short* fn3g = pb + 402176;
    unsigned short* fn3b = pb + 402432;

    probe_kernel<<<1, 256, 0, stream>>>((const unsigned short*)d_in[0], flag);
    cvt_params_kernel<<<512, 256, 0, stream>>>(flag,
        d_in[2], d_in[3], d_in[4], d_in[5], d_in[6], d_in[7], d_in[8], d_in[9],
        d_in[10], d_in[11], d_in[12], d_in[13], d_in[14], d_in[15], d_in[16],
        d_in[17], d_in[18], d_in[19], d_in[20], d_in[21], pb);
    ln_dual_kernel<<<2 * BTOK / 4, 256, 0, stream>>>(d_in[0], d_in[1], n1g, n1b, ln12, flag);
    gemm_bt_kernel<256><<<(2 * BTOK / 32) * (CC / 32) / 4, 256, 0, stream>>>(
        ln12, linw, linb, n12, 2 * BTOK, CC);
    colstats_kernel<<<NBATCH * (CC / 32), 256, 0, stream>>>(nn2, kmax, ksum);
    ctx_kernel<<<NBATCH * 8, 256, 0, stream>>>(nn2, kmax, ksum, ctxb);
    att_kernel<<<NBATCH * 64, 256, 0, stream>>>(nn1, ctxb, attv);
    gemm_bt_kernel<256><<<(BTOK / 32) * (CC / 32) / 4, 256, 0, stream>>>(
        attv, repw, repb, rep, BTOK, CC);
    y_kernel<<<BTOK / 4, 256, 0, stream>>>(rep, d_in[0], ang, anb, g2, b2v, ybuf, flag);
    gemm_bt_kernel<256><<<(BTOK / 32) * (CC2 / 32) / 4, 256, 0, stream>>>(
        ybuf, fc1w, fc1b, h1, BTOK, CC2);
    dw_kernel<<<BTOK / 4, 256, 0, stream>>>(h1, dww, dwb, fn1g, fn1b, axb);
    gemm_bt_kernel<512><<<(BTOK / 32) * (CC / 32) / 4, 256, 0, stream>>>(
        axb, fc2w, fc2b, fout, BTOK, CC);
    final_kernel<<<BTOK / 4, 256, 0, stream>>>(fout, ybuf, fn3g, fn3b, d_out, flag);
}

// Round 4
// 493.317 us; speedup vs baseline: 1.4669x; 1.4669x over previous
//
#include <hip/hip_runtime.h>

#define BTOK 32768   // B*H*W tokens
#define CC 256
#define CC2 512
#define NBATCH 8

typedef __bf16 bf16x8 __attribute__((ext_vector_type(8)));
typedef float f32x4 __attribute__((ext_vector_type(4)));
typedef unsigned short u16x8 __attribute__((ext_vector_type(8)));
typedef unsigned short u16x4 __attribute__((ext_vector_type(4)));

__device__ __forceinline__ float b2f(unsigned short u) {
    return __uint_as_float(((unsigned)u) << 16);
}
__device__ __forceinline__ unsigned short f2b(float f) {
    unsigned x = __float_as_uint(f);
    return (unsigned short)((x + 0x7fffu + ((x >> 16) & 1u)) >> 16);
}
__device__ __forceinline__ float wredsum(float v) {
#pragma unroll
    for (int m = 1; m < 64; m <<= 1) v += __shfl_xor(v, m);
    return v;
}

// ---------------- dtype probe: 1 = bf16 inputs, 0 = f32 inputs ----------------
__global__ __launch_bounds__(256) void probe_kernel(
    const unsigned short* __restrict__ x, int* __restrict__ flag)
{
    int t = threadIdx.x;
    int c = 0;
    for (int i = t; i < 1024; i += 256) {
        unsigned e = (x[i] >> 7) & 0xFFu;
        c += (e >= 110u && e <= 135u) ? 1 : 0;
    }
#pragma unroll
    for (int m = 1; m < 64; m <<= 1) c += __shfl_xor(c, m);
    __shared__ int acc[4];
    if ((t & 63) == 0) acc[t >> 6] = c;
    __syncthreads();
    if (t == 0) *flag = ((acc[0] + acc[1] + acc[2] + acc[3]) >= 896) ? 1 : 0;
}

// ---------------- convert all params to bf16 in ws ----------------
__global__ __launch_bounds__(256) void cvt_params_kernel(
    const int* __restrict__ flagp,
    const void* p0, const void* p1, const void* p2, const void* p3, const void* p4,
    const void* p5, const void* p6, const void* p7, const void* p8, const void* p9,
    const void* p10, const void* p11, const void* p12, const void* p13, const void* p14,
    const void* p15, const void* p16, const void* p17, const void* p18, const void* p19,
    unsigned short* __restrict__ dst)
{
    bool isb = (*flagp != 0);
    long g = (long)blockIdx.x * 256 + threadIdx.x;
    long str = (long)gridDim.x * 256;
#define CVT(src, off, n)                                                        \
    for (long i = g; i < (long)(n); i += str)                                   \
        dst[(off) + i] = isb ? ((const unsigned short*)(src))[i]                \
                             : f2b(((const float*)(src))[i]);
    CVT(p0, 0, 256)          // n1g
    CVT(p1, 256, 256)        // n1b
    CVT(p2, 512, 65536)      // linw
    CVT(p3, 66048, 256)      // linb
    CVT(p4, 66304, 65536)    // repw
    CVT(p5, 131840, 256)     // repb
    CVT(p6, 132096, 256)     // ang
    CVT(p7, 132352, 256)     // anb
    CVT(p8, 132608, 256)     // g2
    CVT(p9, 132864, 256)     // b2v
    CVT(p10, 133120, 131072) // fc1w
    CVT(p11, 264192, 512)    // fc1b
    CVT(p12, 264704, 4608)   // dww
    CVT(p13, 269312, 512)    // dwb
    CVT(p14, 269824, 512)    // fn1g
    CVT(p15, 270336, 512)    // fn1b
    CVT(p16, 270848, 131072) // fc2w
    CVT(p17, 401920, 256)    // fc2b
    CVT(p18, 402176, 256)    // fn3g
    CVT(p19, 402432, 256)    // fn3b
#undef CVT
}

// ---------------- LN of x1 and x2 (shared norm1 params), dtype-aware ----------------
__global__ __launch_bounds__(256) void ln_dual_kernel(
    const void* __restrict__ x1, const void* __restrict__ x2,
    const unsigned short* __restrict__ g, const unsigned short* __restrict__ b,
    unsigned short* __restrict__ out, const int* __restrict__ flagp)
{
    bool isb = (*flagp != 0);
    int wid = threadIdx.x >> 6, l = threadIdx.x & 63;
    long row = (long)blockIdx.x * 4 + wid;   // 0 .. 2*BTOK-1
    const void* xsel = (row < BTOK) ? x1 : x2;
    long r = (row < BTOK) ? row : (row - BTOK);
    float f[4];
    if (isb) {
        u16x4 v = *reinterpret_cast<const u16x4*>((const unsigned short*)xsel + r * CC + l * 4);
#pragma unroll
        for (int j = 0; j < 4; j++) f[j] = b2f(v[j]);
    } else {
        f32x4 v = *reinterpret_cast<const f32x4*>((const float*)xsel + r * CC + l * 4);
#pragma unroll
        for (int j = 0; j < 4; j++) f[j] = v[j];
    }
    float mean = wredsum(f[0] + f[1] + f[2] + f[3]) * (1.f / CC);
    float d[4], sq = 0.f;
#pragma unroll
    for (int j = 0; j < 4; j++) { d[j] = f[j] - mean; sq += d[j] * d[j]; }
    float rs = rsqrtf(wredsum(sq) * (1.f / CC) + 1e-5f);
    u16x4 gv = *reinterpret_cast<const u16x4*>(g + l * 4);
    u16x4 bv = *reinterpret_cast<const u16x4*>(b + l * 4);
    u16x4 o;
#pragma unroll
    for (int j = 0; j < 4; j++) o[j] = f2b(d[j] * rs * b2f(gv[j]) + b2f(bv[j]));
    *reinterpret_cast<u16x4*>(out + row * CC + l * 4) = o;
}

// ---------------- GEMM: out[t][o] = sum_k A[t][k]*W[o][k] + bias[o] ----------------
template<int K>
__global__ __launch_bounds__(256) void gemm_bt_kernel(
    const unsigned short* __restrict__ A, const unsigned short* __restrict__ Wt,
    const unsigned short* __restrict__ bias, unsigned short* __restrict__ out,
    int T, int O)
{
    int l = threadIdx.x & 63;
    int wg = blockIdx.x * 4 + (threadIdx.x >> 6);
    int ntn = O >> 5;
    int tm = (wg / ntn) << 5;
    int tn = (wg % ntn) << 5;
    int rr = l & 15;
    int ko = (l >> 4) << 3;
    const unsigned short* a0 = A + (long)(tm + rr) * K + ko;
    const unsigned short* b0 = Wt + (long)(tn + rr) * K + ko;
    f32x4 acc00 = {0.f, 0.f, 0.f, 0.f};
    f32x4 acc01 = acc00, acc10 = acc00, acc11 = acc00;
    for (int k = 0; k < K; k += 32) {
        bf16x8 af0 = *reinterpret_cast<const bf16x8*>(a0 + k);
        bf16x8 af1 = *reinterpret_cast<const bf16x8*>(a0 + 16 * K + k);
        bf16x8 bv0 = *reinterpret_cast<const bf16x8*>(b0 + k);
        bf16x8 bv1 = *reinterpret_cast<const bf16x8*>(b0 + 16 * K + k);
        acc00 = __builtin_amdgcn_mfma_f32_16x16x32_bf16(af0, bv0, acc00, 0, 0, 0);
        acc01 = __builtin_amdgcn_mfma_f32_16x16x32_bf16(af0, bv1, acc01, 0, 0, 0);
        acc10 = __builtin_amdgcn_mfma_f32_16x16x32_bf16(af1, bv0, acc10, 0, 0, 0);
        acc11 = __builtin_amdgcn_mfma_f32_16x16x32_bf16(af1, bv1, acc11, 0, 0, 0);
    }
    int orow = (l >> 4) << 2;
    int ocol = l & 15;
    float bi0 = b2f(bias[tn + ocol]);
    float bi1 = b2f(bias[tn + 16 + ocol]);
#pragma unroll
    for (int j = 0; j < 4; j++) {
        out[(long)(tm + orow + j) * O + tn + ocol]           = f2b(acc00[j] + bi0);
        out[(long)(tm + orow + j) * O + tn + 16 + ocol]      = f2b(acc01[j] + bi1);
        out[(long)(tm + 16 + orow + j) * O + tn + ocol]      = f2b(acc10[j] + bi0);
        out[(long)(tm + 16 + orow + j) * O + tn + 16 + ocol] = f2b(acc11[j] + bi1);
    }
}

// ---------------- colstats stage 1: per-slab online (max,sum) ----------------
// grid: NBATCH*64 blocks; slab = 64 tokens; thread owns 4 channels.
__global__ __launch_bounds__(256) void colstats1_kernel(
    const unsigned short* __restrict__ n2, float* __restrict__ pm, float* __restrict__ ps)
{
    int b = blockIdx.x >> 6, slab = blockIdx.x & 63;
    int t = threadIdx.x;
    int c0 = (t & 63) << 2;
    int r = t >> 6;                      // wave id: starting row
    const unsigned short* base = n2 + ((long)b * 4096 + slab * 64 + r) * CC + c0;
    float m[4] = {-3.0e38f, -3.0e38f, -3.0e38f, -3.0e38f};
    float s[4] = {0.f, 0.f, 0.f, 0.f};
#pragma unroll 4
    for (int i = 0; i < 16; i++) {
        u16x4 v = *reinterpret_cast<const u16x4*>(base + (long)i * 4 * CC);
#pragma unroll
        for (int j = 0; j < 4; j++) {
            float x = b2f(v[j]);
            if (x > m[j]) { s[j] = s[j] * __expf(m[j] - x) + 1.f; m[j] = x; }
            else s[j] += __expf(x - m[j]);
        }
    }
    __shared__ float lm[4][256], lsb[4][256];
#pragma unroll
    for (int j = 0; j < 4; j++) { lm[r][c0 + j] = m[j]; lsb[r][c0 + j] = s[j]; }
    __syncthreads();
    if (r == 0) {
#pragma unroll
        for (int w = 1; w < 4; w++) {
#pragma unroll
            for (int j = 0; j < 4; j++) {
                float mi = lm[w][c0 + j], si = lsb[w][c0 + j];
                if (mi > m[j]) { s[j] = s[j] * __expf(m[j] - mi) + si; m[j] = mi; }
                else s[j] += si * __expf(mi - m[j]);
            }
        }
        long o = ((long)(b * 64 + slab)) * 256 + c0;
#pragma unroll
        for (int j = 0; j < 4; j++) { pm[o + j] = m[j]; ps[o + j] = s[j]; }
    }
}

// ---------------- colstats stage 2: merge 64 slabs ----------------
__global__ __launch_bounds__(256) void colstats2_kernel(
    const float* __restrict__ pm, const float* __restrict__ ps,
    float* __restrict__ kmax, float* __restrict__ ksum)
{
    int b = blockIdx.x, c = threadIdx.x;
    float M = -3.0e38f, S = 0.f;
    for (int s = 0; s < 64; s++) {
        long o = ((long)(b * 64 + s)) * 256 + c;
        float mi = pm[o], si = ps[o];
        if (mi > M) { S = S * __expf(M - mi) + si; M = mi; }
        else S += si * __expf(mi - M);
    }
    kmax[b * CC + c] = M;
    ksum[b * CC + c] = S;
}

// ---------------- ctx partial: slab of 256 tokens per block ----------------
// pctx[slab][((b*8+hd)*32+d)*32+v]
__global__ __launch_bounds__(256) void ctx_part_kernel(
    const unsigned short* __restrict__ n2, const float* __restrict__ kmax,
    const float* __restrict__ ksum, float* __restrict__ pctx)
{
    int blk = blockIdx.x;
    int b = blk >> 7, hd = (blk >> 4) & 7, slab = blk & 15;
    int t = threadIdx.x;
    __shared__ float ld[32][33], eld[32][33];
    int d = t >> 3;
    int v0 = (t & 7) << 2;
    int ln_ = t >> 3;
    int lc = (t & 7) << 2;
    float kmx4[4], kin4[4];
#pragma unroll
    for (int j = 0; j < 4; j++) {
        kmx4[j] = kmax[b * CC + hd * 32 + lc + j];
        kin4[j] = 1.f / ksum[b * CC + hd * 32 + lc + j];
    }
    f32x4 acc = {0.f, 0.f, 0.f, 0.f};
    const unsigned short* base = n2 + ((long)b * 4096 + slab * 256) * CC + hd * 32;
    for (int n0 = 0; n0 < 256; n0 += 32) {
        u16x4 rv = *reinterpret_cast<const u16x4*>(base + (long)(n0 + ln_) * CC + lc);
#pragma unroll
        for (int j = 0; j < 4; j++) {
            float x = b2f(rv[j]);
            ld[ln_][lc + j] = x;
            eld[ln_][lc + j] = __expf(x - kmx4[j]) * kin4[j];
        }
        __syncthreads();
#pragma unroll 4
        for (int nn = 0; nn < 32; nn++) {
            float e = eld[nn][d];
#pragma unroll
            for (int j = 0; j < 4; j++) acc[j] += e * ld[nn][v0 + j];
        }
        __syncthreads();
    }
    long o = ((long)slab * NBATCH * 8 + (long)b * 8 + hd) * 1024 + (long)d * 32 + v0;
#pragma unroll
    for (int j = 0; j < 4; j++) pctx[o + j] = acc[j];
}

// ---------------- ctx reduce: sum 16 slab partials ----------------
__global__ __launch_bounds__(256) void ctx_reduce_kernel(
    const float* __restrict__ pctx, float* __restrict__ ctx)
{
    long i = (long)blockIdx.x * 256 + threadIdx.x;   // 65536 elements
    float s = 0.f;
#pragma unroll
    for (int sl = 0; sl < 16; sl++) s += pctx[(long)sl * 65536 + i];
    ctx[i] = s;
}

// ---------------- q-softmax + att = ctx^T q, per token ----------------
__global__ __launch_bounds__(256) void att_kernel(
    const unsigned short* __restrict__ n1, const float* __restrict__ ctx,
    unsigned short* __restrict__ attv)
{
    __shared__ float cl[32 * 256];
    __shared__ float ql[4][264];
    int b = blockIdx.x >> 6, grp = blockIdx.x & 63;
    int t = threadIdx.x, wid = t >> 6, l = t & 63;
    const float* cb = ctx + (long)b * 8192;
    for (int i = 0; i < 32; i++) {
        int gidx = t + (i << 8);
        int hd_ = gidx >> 10, dd = (gidx >> 5) & 31, vv = gidx & 31;
        cl[dd * 256 + hd_ * 32 + vv] = cb[gidx];
    }
    __syncthreads();
    int hd = l >> 3;
    long tokbase = (long)b * 4096 + grp * 64 + wid * 16;
    const f32x4* c4 = reinterpret_cast<const f32x4*>(cl);
    for (int it = 0; it < 16; it++) {
        long tok = tokbase + it;
        u16x4 rv = *reinterpret_cast<const u16x4*>(n1 + tok * CC + l * 4);
        float x[4];
#pragma unroll
        for (int j = 0; j < 4; j++) x[j] = b2f(rv[j]);
        float mx = fmaxf(fmaxf(x[0], x[1]), fmaxf(x[2], x[3]));
        mx = fmaxf(mx, __shfl_xor(mx, 1));
        mx = fmaxf(mx, __shfl_xor(mx, 2));
        mx = fmaxf(mx, __shfl_xor(mx, 4));
        float e[4], s = 0.f;
#pragma unroll
        for (int j = 0; j < 4; j++) { e[j] = __expf(x[j] - mx); s += e[j]; }
        s += __shfl_xor(s, 1);
        s += __shfl_xor(s, 2);
        s += __shfl_xor(s, 4);
        float inv = 1.f / s;
#pragma unroll
        for (int j = 0; j < 4; j++) ql[wid][hd * 33 + ((l & 7) << 2) + j] = e[j] * inv;
        __syncthreads();
        f32x4 o = {0.f, 0.f, 0.f, 0.f};
#pragma unroll 8
        for (int dd = 0; dd < 32; dd++) {
            float qd = ql[wid][hd * 33 + dd];
            o += qd * c4[dd * 64 + l];
        }
        __syncthreads();
        u16x4 ov;
#pragma unroll
        for (int j = 0; j < 4; j++) ov[j] = f2b(o[j]);
        *reinterpret_cast<u16x4*>(attv + tok * CC + l * 4) = ov;
    }
}

// ---------------- attn_out = LN(rep); y = LN(attn_out + x1), dtype-aware x1 ----------------
__global__ __launch_bounds__(256) void y_kernel(
    const unsigned short* __restrict__ rep, const void* __restrict__ x1,
    const unsigned short* __restrict__ ag, const unsigned short* __restrict__ ab,
    const unsigned short* __restrict__ g2, const unsigned short* __restrict__ b2v,
    unsigned short* __restrict__ yout, const int* __restrict__ flagp)
{
    bool isb = (*flagp != 0);
    int wid = threadIdx.x >> 6, l = threadIdx.x & 63;
    long tok = (long)blockIdx.x * 4 + wid;
    long base = tok * CC + l * 4;
    u16x4 rv = *reinterpret_cast<const u16x4*>(rep + base);
    float f[4];
#pragma unroll
    for (int j = 0; j < 4; j++) f[j] = b2f(rv[j]);
    float mean = wredsum(f[0] + f[1] + f[2] + f[3]) * (1.f / CC);
    float d[4], sq = 0.f;
#pragma unroll
    for (int j = 0; j < 4; j++) { d[j] = f[j] - mean; sq += d[j] * d[j]; }
    float rs = rsqrtf(wredsum(sq) * (1.f / CC) + 1e-5f);
    u16x4 gv = *reinterpret_cast<const u16x4*>(ag + l * 4);
    u16x4 bv = *reinterpret_cast<const u16x4*>(ab + l * 4);
    float xv[4];
    if (isb) {
        u16x4 x4v = *reinterpret_cast<const u16x4*>((const unsigned short*)x1 + base);
#pragma unroll
        for (int j = 0; j < 4; j++) xv[j] = b2f(x4v[j]);
    } else {
        f32x4 x4v = *reinterpret_cast<const f32x4*>((const float*)x1 + base);
#pragma unroll
        for (int j = 0; j < 4; j++) xv[j] = x4v[j];
    }
    float tt[4];
#pragma unroll
    for (int j = 0; j < 4; j++) tt[j] = d[j] * rs * b2f(gv[j]) + b2f(bv[j]) + xv[j];
    float mean2 = wredsum(tt[0] + tt[1] + tt[2] + tt[3]) * (1.f / CC);
    float d2[4], sq2 = 0.f;
#pragma unroll
    for (int j = 0; j < 4; j++) { d2[j] = tt[j] - mean2; sq2 += d2[j] * d2[j]; }
    float rs2 = rsqrtf(wredsum(sq2) * (1.f / CC) + 1e-5f);
    u16x4 gv2 = *reinterpret_cast<const u16x4*>(g2 + l * 4);
    u16x4 bv2 = *reinterpret_cast<const u16x4*>(b2v + l * 4);
    u16x4 o;
#pragma unroll
    for (int j = 0; j < 4; j++) o[j] = f2b(d2[j] * rs2 * b2f(gv2[j]) + b2f(bv2[j]));
    *reinterpret_cast<u16x4*>(yout + base) = o;
}

// ---------------- depthwise 3x3 conv + LN + exact GELU ----------------
__global__ __launch_bounds__(256) void dw_kernel(
    const unsigned short* __restrict__ h1, const unsigned short* __restrict__ dww,
    const unsigned short* __restrict__ dwb, const unsigned short* __restrict__ g,
    const unsigned short* __restrict__ bb, unsigned short* __restrict__ ax)
{
    int wid = threadIdx.x >> 6, l = threadIdx.x & 63;
    int pix = blockIdx.x * 4 + wid;
    int b = pix >> 12, rem = pix & 4095, py = rem >> 6, px = rem & 63;
    int c0 = l * 8;
    float acc[8];
#pragma unroll
    for (int j = 0; j < 8; j++) acc[j] = b2f(dwb[c0 + j]);
#pragma unroll
    for (int ky = 0; ky < 3; ky++) {
        int ys = py + ky - 1;
        if ((unsigned)ys >= 64u) continue;
#pragma unroll
        for (int kx = 0; kx < 3; kx++) {
            int xs = px + kx - 1;
            if ((unsigned)xs >= 64u) continue;
            u16x8 pv = *reinterpret_cast<const u16x8*>(
                h1 + ((long)(b << 12) + (ys << 6) + xs) * CC2 + c0);
#pragma unroll
            for (int j = 0; j < 8; j++)
                acc[j] += b2f(pv[j]) * b2f(dww[(c0 + j) * 9 + ky * 3 + kx]);
        }
    }
    float s = 0.f;
#pragma unroll
    for (int j = 0; j < 8; j++) s += acc[j];
    float mean = wredsum(s) * (1.f / CC2);
    float d[8], sq = 0.f;
#pragma unroll
    for (int j = 0; j < 8; j++) { d[j] = acc[j] - mean; sq += d[j] * d[j]; }
    float rs = rsqrtf(wredsum(sq) * (1.f / CC2) + 1e-5f);
    u16x8 gv = *reinterpret_cast<const u16x8*>(g + c0);
    u16x8 bv = *reinterpret_cast<const u16x8*>(bb + c0);
    u16x8 o;
#pragma unroll
    for (int j = 0; j < 8; j++) {
        float nv = d[j] * rs * b2f(gv[j]) + b2f(bv[j]);
        o[j] = f2b(0.5f * nv * (1.f + erff(nv * 0.70710678118654752f)));
    }
    *reinterpret_cast<u16x8*>(ax + (long)pix * CC2 + c0) = o;
}

// ---------------- final: out = LN(fout + y), dtype-aware output ----------------
__global__ __launch_bounds__(256) void final_kernel(
    const unsigned short* __restrict__ fout, const unsigned short* __restrict__ y,
    const unsigned short* __restrict__ g, const unsigned short* __restrict__ bb,
    void* __restrict__ out, const int* __restrict__ flagp)
{
    bool isb = (*flagp != 0);
    int wid = threadIdx.x >> 6, l = threadIdx.x & 63;
    long tok = (long)blockIdx.x * 4 + wid;
    long base = tok * CC + l * 4;
    u16x4 fv = *reinterpret_cast<const u16x4*>(fout + base);
    u16x4 yv = *reinterpret_cast<const u16x4*>(y + base);
    float f[4];
#pragma unroll
    for (int j = 0; j < 4; j++) f[j] = b2f(fv[j]) + b2f(yv[j]);
    float mean = wredsum(f[0] + f[1] + f[2] + f[3]) * (1.f / CC);
    float d[4], sq = 0.f;
#pragma unroll
    for (int j = 0; j < 4; j++) { d[j] = f[j] - mean; sq += d[j] * d[j]; }
    float rs = rsqrtf(wredsum(sq) * (1.f / CC) + 1e-5f);
    u16x4 gv = *reinterpret_cast<const u16x4*>(g + l * 4);
    u16x4 bv = *reinterpret_cast<const u16x4*>(bb + l * 4);
    float r[4];
#pragma unroll
    for (int j = 0; j < 4; j++) r[j] = d[j] * rs * b2f(gv[j]) + b2f(bv[j]);
    if (isb) {
        u16x4 o;
#pragma unroll
        for (int j = 0; j < 4; j++) o[j] = f2b(r[j]);
        *reinterpret_cast<u16x4*>((unsigned short*)out + base) = o;
    } else {
        f32x4 o;
#pragma unroll
        for (int j = 0; j < 4; j++) o[j] = r[j];
        *reinterpret_cast<f32x4*>((float*)out + base) = o;
    }
}

extern "C" void kernel_launch(void* const* d_in, const int* in_sizes, int n_in,
                              void* d_out, int out_size, void* d_ws, size_t ws_size,
                              hipStream_t stream)
{
    char* w = (char*)d_ws;
    const size_t S1B = (size_t)BTOK * CC * 2;   // 16.78 MB
    const size_t STATSB = (size_t)(2 * NBATCH * CC + NBATCH * 8 * 32 * 32) * 4;
    const size_t PARAMS_ELEMS = 402688;
    const size_t need = 6 * S1B + STATSB + 64 + PARAMS_ELEMS * 2;
    if (ws_size < need) return;

    unsigned short* ln12 = (unsigned short*)w;
    unsigned short* n12  = (unsigned short*)(w + 2 * S1B);
    unsigned short* nn1  = n12;
    unsigned short* nn2  = n12 + (size_t)BTOK * CC;
    unsigned short* attv = ln12;
    unsigned short* rep  = ln12 + (size_t)BTOK * CC;
    unsigned short* ybuf = nn1;
    unsigned short* fout = nn2;
    unsigned short* h1   = ln12;
    unsigned short* axb  = (unsigned short*)(w + 4 * S1B);
    // transient scratch inside the (not-yet-used) axb region:
    float* pm   = (float*)(w + 4 * S1B);                 // 512 KB
    float* ps   = (float*)(w + 4 * S1B + (512 << 10));   // 512 KB
    float* pctx = (float*)(w + 4 * S1B + (2048 << 10));  // 4 MB (16 x 256 KB)
    float* kmax = (float*)(w + 6 * S1B);
    float* ksum = kmax + NBATCH * CC;
    float* ctxb = ksum + NBATCH * CC;
    int*   flag = (int*)(w + 6 * S1B + STATSB);
    unsigned short* pb = (unsigned short*)(w + 6 * S1B + STATSB + 64);

    // bf16 param block offsets
    unsigned short* n1g  = pb + 0;
    unsigned short* n1b  = pb + 256;
    unsigned short* linw = pb + 512;
    unsigned short* linb = pb + 66048;
    unsigned short* repw = pb + 66304;
    unsigned short* repb = pb + 131840;
    unsigned short* ang  = pb + 132096;
    unsigned short* anb  = pb + 132352;
    unsigned short* g2   = pb + 132608;
    unsigned short* b2v  = pb + 132864;
    unsigned short* fc1w = pb + 133120;
    unsigned short* fc1b = pb + 264192;
    unsigned short* dww  = pb + 264704;
    unsigned short* dwb  = pb + 269312;
    unsigned short* fn1g = pb + 269824;
    unsigned short* fn1b = pb + 270336;
    unsigned short* fc2w = pb + 270848;
    unsigned short* fc2b = pb + 401920;
    unsigned short* fn3g = pb + 402176;
    unsigned short* fn3b = pb + 402432;

    probe_kernel<<<1, 256, 0, stream>>>((const unsigned short*)d_in[0], flag);
    cvt_params_kernel<<<512, 256, 0, stream>>>(flag,
        d_in[2], d_in[3], d_in[4], d_in[5], d_in[6], d_in[7], d_in[8], d_in[9],
        d_in[10], d_in[11], d_in[12], d_in[13], d_in[14], d_in[15], d_in[16],
        d_in[17], d_in[18], d_in[19], d_in[20], d_in[21], pb);
    ln_dual_kernel<<<2 * BTOK / 4, 256, 0, stream>>>(d_in[0], d_in[1], n1g, n1b, ln12, flag);
    gemm_bt_kernel<256><<<(2 * BTOK / 32) * (CC / 32) / 4, 256, 0, stream>>>(
        ln12, linw, linb, n12, 2 * BTOK, CC);
    colstats1_kernel<<<NBATCH * 64, 256, 0, stream>>>(nn2, pm, ps);
    colstats2_kernel<<<NBATCH, 256, 0, stream>>>(pm, ps, kmax, ksum);
    ctx_part_kernel<<<NBATCH * 8 * 16, 256, 0, stream>>>(nn2, kmax, ksum, pctx);
    ctx_reduce_kernel<<<256, 256, 0, stream>>>(pctx, ctxb);
    att_kernel<<<NBATCH * 64, 256, 0, stream>>>(nn1, ctxb, attv);
    gemm_bt_kernel<256><<<(BTOK / 32) * (CC / 32) / 4, 256, 0, stream>>>(
        attv, repw, repb, rep, BTOK, CC);
    y_kernel<<<BTOK / 4, 256, 0, stream>>>(rep, d_in[0], ang, anb, g2, b2v, ybuf, flag);
    gemm_bt_kernel<256><<<(BTOK / 32) * (CC2 / 32) / 4, 256, 0, stream>>>(
        ybuf, fc1w, fc1b, h1, BTOK, CC2);
    dw_kernel<<<BTOK / 4, 256, 0, stream>>>(h1, dww, dwb, fn1g, fn1b, axb);
    gemm_bt_kernel<512><<<(BTOK / 32) * (CC / 32) / 4, 256, 0, stream>>>(
        axb, fc2w, fc2b, fout, BTOK, CC);
    final_kernel<<<BTOK / 4, 256, 0, stream>>>(fout, ybuf, fn3g, fn3b, d_out, flag);
}

// Round 5
// 390.410 us; speedup vs baseline: 1.8535x; 1.2636x over previous
//
#include <hip/hip_runtime.h>

#define BTOK 32768   // B*H*W tokens
#define CC 256
#define CC2 512
#define NBATCH 8

typedef __bf16 bf16x8 __attribute__((ext_vector_type(8)));
typedef float f32x4 __attribute__((ext_vector_type(4)));
typedef unsigned short u16x8 __attribute__((ext_vector_type(8)));
typedef unsigned short u16x4 __attribute__((ext_vector_type(4)));

__device__ __forceinline__ float b2f(unsigned short u) {
    return __uint_as_float(((unsigned)u) << 16);
}
__device__ __forceinline__ unsigned short f2b(float f) {
    unsigned x = __float_as_uint(f);
    return (unsigned short)((x + 0x7fffu + ((x >> 16) & 1u)) >> 16);
}
__device__ __forceinline__ float wredsum(float v) {
#pragma unroll
    for (int m = 1; m < 64; m <<= 1) v += __shfl_xor(v, m);
    return v;
}

// ---------------- dtype probe: 1 = bf16 inputs, 0 = f32 inputs ----------------
__global__ __launch_bounds__(256) void probe_kernel(
    const unsigned short* __restrict__ x, int* __restrict__ flag)
{
    int t = threadIdx.x;
    int c = 0;
    for (int i = t; i < 1024; i += 256) {
        unsigned e = (x[i] >> 7) & 0xFFu;
        c += (e >= 110u && e <= 135u) ? 1 : 0;
    }
#pragma unroll
    for (int m = 1; m < 64; m <<= 1) c += __shfl_xor(c, m);
    __shared__ int acc[4];
    if ((t & 63) == 0) acc[t >> 6] = c;
    __syncthreads();
    if (t == 0) *flag = ((acc[0] + acc[1] + acc[2] + acc[3]) >= 896) ? 1 : 0;
}

// ---------------- convert all params to bf16 in ws ----------------
__global__ __launch_bounds__(256) void cvt_params_kernel(
    const int* __restrict__ flagp,
    const void* p0, const void* p1, const void* p2, const void* p3, const void* p4,
    const void* p5, const void* p6, const void* p7, const void* p8, const void* p9,
    const void* p10, const void* p11, const void* p12, const void* p13, const void* p14,
    const void* p15, const void* p16, const void* p17, const void* p18, const void* p19,
    unsigned short* __restrict__ dst)
{
    bool isb = (*flagp != 0);
    long g = (long)blockIdx.x * 256 + threadIdx.x;
    long str = (long)gridDim.x * 256;
#define CVT(src, off, n)                                                        \
    for (long i = g; i < (long)(n); i += str)                                   \
        dst[(off) + i] = isb ? ((const unsigned short*)(src))[i]                \
                             : f2b(((const float*)(src))[i]);
    CVT(p0, 0, 256)          // n1g
    CVT(p1, 256, 256)        // n1b
    CVT(p2, 512, 65536)      // linw
    CVT(p3, 66048, 256)      // linb
    CVT(p4, 66304, 65536)    // repw
    CVT(p5, 131840, 256)     // repb
    CVT(p6, 132096, 256)     // ang
    CVT(p7, 132352, 256)     // anb
    CVT(p8, 132608, 256)     // g2
    CVT(p9, 132864, 256)     // b2v
    CVT(p10, 133120, 131072) // fc1w
    CVT(p11, 264192, 512)    // fc1b
    CVT(p12, 264704, 4608)   // dww
    CVT(p13, 269312, 512)    // dwb
    CVT(p14, 269824, 512)    // fn1g
    CVT(p15, 270336, 512)    // fn1b
    CVT(p16, 270848, 131072) // fc2w
    CVT(p17, 401920, 256)    // fc2b
    CVT(p18, 402176, 256)    // fn3g
    CVT(p19, 402432, 256)    // fn3b
#undef CVT
}

// ---------------- transpose dw weights: dwt[tap][c] = dww[c][tap] ----------------
__global__ __launch_bounds__(256) void dw_transpose_kernel(
    const void* __restrict__ src, unsigned short* __restrict__ dwt,
    const int* __restrict__ flagp)
{
    bool isb = (*flagp != 0);
    for (int i = threadIdx.x; i < 4608; i += 256) {
        int tap = i >> 9, c = i & 511;
        dwt[i] = isb ? ((const unsigned short*)src)[c * 9 + tap]
                     : f2b(((const float*)src)[c * 9 + tap]);
    }
}

// ---------------- LN of x1 and x2 (shared norm1 params), dtype-aware ----------------
__global__ __launch_bounds__(256) void ln_dual_kernel(
    const void* __restrict__ x1, const void* __restrict__ x2,
    const unsigned short* __restrict__ g, const unsigned short* __restrict__ b,
    unsigned short* __restrict__ out, const int* __restrict__ flagp)
{
    bool isb = (*flagp != 0);
    int wid = threadIdx.x >> 6, l = threadIdx.x & 63;
    long row = (long)blockIdx.x * 4 + wid;   // 0 .. 2*BTOK-1
    const void* xsel = (row < BTOK) ? x1 : x2;
    long r = (row < BTOK) ? row : (row - BTOK);
    float f[4];
    if (isb) {
        u16x4 v = *reinterpret_cast<const u16x4*>((const unsigned short*)xsel + r * CC + l * 4);
#pragma unroll
        for (int j = 0; j < 4; j++) f[j] = b2f(v[j]);
    } else {
        f32x4 v = *reinterpret_cast<const f32x4*>((const float*)xsel + r * CC + l * 4);
#pragma unroll
        for (int j = 0; j < 4; j++) f[j] = v[j];
    }
    float mean = wredsum(f[0] + f[1] + f[2] + f[3]) * (1.f / CC);
    float d[4], sq = 0.f;
#pragma unroll
    for (int j = 0; j < 4; j++) { d[j] = f[j] - mean; sq += d[j] * d[j]; }
    float rs = rsqrtf(wredsum(sq) * (1.f / CC) + 1e-5f);
    u16x4 gv = *reinterpret_cast<const u16x4*>(g + l * 4);
    u16x4 bv = *reinterpret_cast<const u16x4*>(b + l * 4);
    u16x4 o;
#pragma unroll
    for (int j = 0; j < 4; j++) o[j] = f2b(d[j] * rs * b2f(gv[j]) + b2f(bv[j]));
    *reinterpret_cast<u16x4*>(out + row * CC + l * 4) = o;
}

// ---------------- GEMM: out[t][o] = sum_k A[t][k]*W[o][k] + bias[o] ----------------
template<int K>
__global__ __launch_bounds__(256) void gemm_bt_kernel(
    const unsigned short* __restrict__ A, const unsigned short* __restrict__ Wt,
    const unsigned short* __restrict__ bias, unsigned short* __restrict__ out,
    int T, int O)
{
    int l = threadIdx.x & 63;
    int wg = blockIdx.x * 4 + (threadIdx.x >> 6);
    int ntn = O >> 5;
    int tm = (wg / ntn) << 5;
    int tn = (wg % ntn) << 5;
    int rr = l & 15;
    int ko = (l >> 4) << 3;
    const unsigned short* a0 = A + (long)(tm + rr) * K + ko;
    const unsigned short* b0 = Wt + (long)(tn + rr) * K + ko;
    f32x4 acc00 = {0.f, 0.f, 0.f, 0.f};
    f32x4 acc01 = acc00, acc10 = acc00, acc11 = acc00;
    for (int k = 0; k < K; k += 32) {
        bf16x8 af0 = *reinterpret_cast<const bf16x8*>(a0 + k);
        bf16x8 af1 = *reinterpret_cast<const bf16x8*>(a0 + 16 * K + k);
        bf16x8 bv0 = *reinterpret_cast<const bf16x8*>(b0 + k);
        bf16x8 bv1 = *reinterpret_cast<const bf16x8*>(b0 + 16 * K + k);
        acc00 = __builtin_amdgcn_mfma_f32_16x16x32_bf16(af0, bv0, acc00, 0, 0, 0);
        acc01 = __builtin_amdgcn_mfma_f32_16x16x32_bf16(af0, bv1, acc01, 0, 0, 0);
        acc10 = __builtin_amdgcn_mfma_f32_16x16x32_bf16(af1, bv0, acc10, 0, 0, 0);
        acc11 = __builtin_amdgcn_mfma_f32_16x16x32_bf16(af1, bv1, acc11, 0, 0, 0);
    }
    int orow = (l >> 4) << 2;
    int ocol = l & 15;
    float bi0 = b2f(bias[tn + ocol]);
    float bi1 = b2f(bias[tn + 16 + ocol]);
#pragma unroll
    for (int j = 0; j < 4; j++) {
        out[(long)(tm + orow + j) * O + tn + ocol]           = f2b(acc00[j] + bi0);
        out[(long)(tm + orow + j) * O + tn + 16 + ocol]      = f2b(acc01[j] + bi1);
        out[(long)(tm + 16 + orow + j) * O + tn + ocol]      = f2b(acc10[j] + bi0);
        out[(long)(tm + 16 + orow + j) * O + tn + 16 + ocol] = f2b(acc11[j] + bi1);
    }
}

// ---------------- colstats stage 1: per-slab online (max,sum) ----------------
__global__ __launch_bounds__(256) void colstats1_kernel(
    const unsigned short* __restrict__ n2, float* __restrict__ pm, float* __restrict__ ps)
{
    int b = blockIdx.x >> 6, slab = blockIdx.x & 63;
    int t = threadIdx.x;
    int c0 = (t & 63) << 2;
    int r = t >> 6;
    const unsigned short* base = n2 + ((long)b * 4096 + slab * 64 + r) * CC + c0;
    float m[4] = {-3.0e38f, -3.0e38f, -3.0e38f, -3.0e38f};
    float s[4] = {0.f, 0.f, 0.f, 0.f};
#pragma unroll 4
    for (int i = 0; i < 16; i++) {
        u16x4 v = *reinterpret_cast<const u16x4*>(base + (long)i * 4 * CC);
#pragma unroll
        for (int j = 0; j < 4; j++) {
            float x = b2f(v[j]);
            if (x > m[j]) { s[j] = s[j] * __expf(m[j] - x) + 1.f; m[j] = x; }
            else s[j] += __expf(x - m[j]);
        }
    }
    __shared__ float lm[4][256], lsb[4][256];
#pragma unroll
    for (int j = 0; j < 4; j++) { lm[r][c0 + j] = m[j]; lsb[r][c0 + j] = s[j]; }
    __syncthreads();
    if (r == 0) {
#pragma unroll
        for (int w = 1; w < 4; w++) {
#pragma unroll
            for (int j = 0; j < 4; j++) {
                float mi = lm[w][c0 + j], si = lsb[w][c0 + j];
                if (mi > m[j]) { s[j] = s[j] * __expf(m[j] - mi) + si; m[j] = mi; }
                else s[j] += si * __expf(mi - m[j]);
            }
        }
        long o = ((long)(b * 64 + slab)) * 256 + c0;
#pragma unroll
        for (int j = 0; j < 4; j++) { pm[o + j] = m[j]; ps[o + j] = s[j]; }
    }
}

// ---------------- colstats stage 2: merge 64 slabs ----------------
__global__ __launch_bounds__(256) void colstats2_kernel(
    const float* __restrict__ pm, const float* __restrict__ ps,
    float* __restrict__ kmax, float* __restrict__ ksum)
{
    int b = blockIdx.x, c = threadIdx.x;
    float M = -3.0e38f, S = 0.f;
    for (int s = 0; s < 64; s++) {
        long o = ((long)(b * 64 + s)) * 256 + c;
        float mi = pm[o], si = ps[o];
        if (mi > M) { S = S * __expf(M - mi) + si; M = mi; }
        else S += si * __expf(mi - M);
    }
    kmax[b * CC + c] = M;
    ksum[b * CC + c] = S;
}

// ---------------- ctx partial: slab of 256 tokens per block ----------------
__global__ __launch_bounds__(256) void ctx_part_kernel(
    const unsigned short* __restrict__ n2, const float* __restrict__ kmax,
    const float* __restrict__ ksum, float* __restrict__ pctx)
{
    int blk = blockIdx.x;
    int b = blk >> 7, hd = (blk >> 4) & 7, slab = blk & 15;
    int t = threadIdx.x;
    __shared__ float ld[32][33], eld[32][33];
    int d = t >> 3;
    int v0 = (t & 7) << 2;
    int ln_ = t >> 3;
    int lc = (t & 7) << 2;
    float kmx4[4], kin4[4];
#pragma unroll
    for (int j = 0; j < 4; j++) {
        kmx4[j] = kmax[b * CC + hd * 32 + lc + j];
        kin4[j] = 1.f / ksum[b * CC + hd * 32 + lc + j];
    }
    f32x4 acc = {0.f, 0.f, 0.f, 0.f};
    const unsigned short* base = n2 + ((long)b * 4096 + slab * 256) * CC + hd * 32;
    for (int n0 = 0; n0 < 256; n0 += 32) {
        u16x4 rv = *reinterpret_cast<const u16x4*>(base + (long)(n0 + ln_) * CC + lc);
#pragma unroll
        for (int j = 0; j < 4; j++) {
            float x = b2f(rv[j]);
            ld[ln_][lc + j] = x;
            eld[ln_][lc + j] = __expf(x - kmx4[j]) * kin4[j];
        }
        __syncthreads();
#pragma unroll 4
        for (int nn = 0; nn < 32; nn++) {
            float e = eld[nn][d];
#pragma unroll
            for (int j = 0; j < 4; j++) acc[j] += e * ld[nn][v0 + j];
        }
        __syncthreads();
    }
    long o = ((long)slab * NBATCH * 8 + (long)b * 8 + hd) * 1024 + (long)d * 32 + v0;
#pragma unroll
    for (int j = 0; j < 4; j++) pctx[o + j] = acc[j];
}

// ---------------- ctx reduce: sum 16 slab partials ----------------
__global__ __launch_bounds__(256) void ctx_reduce_kernel(
    const float* __restrict__ pctx, float* __restrict__ ctx)
{
    long i = (long)blockIdx.x * 256 + threadIdx.x;
    float s = 0.f;
#pragma unroll
    for (int sl = 0; sl < 16; sl++) s += pctx[(long)sl * 65536 + i];
    ctx[i] = s;
}

// ---------------- q-softmax + att = ctx^T q, per token ----------------
__global__ __launch_bounds__(256) void att_kernel(
    const unsigned short* __restrict__ n1, const float* __restrict__ ctx,
    unsigned short* __restrict__ attv)
{
    __shared__ float cl[32 * 256];
    __shared__ float ql[4][264];
    int b = blockIdx.x >> 6, grp = blockIdx.x & 63;
    int t = threadIdx.x, wid = t >> 6, l = t & 63;
    const float* cb = ctx + (long)b * 8192;
    for (int i = 0; i < 32; i++) {
        int gidx = t + (i << 8);
        int hd_ = gidx >> 10, dd = (gidx >> 5) & 31, vv = gidx & 31;
        cl[dd * 256 + hd_ * 32 + vv] = cb[gidx];
    }
    __syncthreads();
    int hd = l >> 3;
    long tokbase = (long)b * 4096 + grp * 64 + wid * 16;
    const f32x4* c4 = reinterpret_cast<const f32x4*>(cl);
    for (int it = 0; it < 16; it++) {
        long tok = tokbase + it;
        u16x4 rv = *reinterpret_cast<const u16x4*>(n1 + tok * CC + l * 4);
        float x[4];
#pragma unroll
        for (int j = 0; j < 4; j++) x[j] = b2f(rv[j]);
        float mx = fmaxf(fmaxf(x[0], x[1]), fmaxf(x[2], x[3]));
        mx = fmaxf(mx, __shfl_xor(mx, 1));
        mx = fmaxf(mx, __shfl_xor(mx, 2));
        mx = fmaxf(mx, __shfl_xor(mx, 4));
        float e[4], s = 0.f;
#pragma unroll
        for (int j = 0; j < 4; j++) { e[j] = __expf(x[j] - mx); s += e[j]; }
        s += __shfl_xor(s, 1);
        s += __shfl_xor(s, 2);
        s += __shfl_xor(s, 4);
        float inv = 1.f / s;
#pragma unroll
        for (int j = 0; j < 4; j++) ql[wid][hd * 33 + ((l & 7) << 2) + j] = e[j] * inv;
        __syncthreads();
        f32x4 o = {0.f, 0.f, 0.f, 0.f};
#pragma unroll 8
        for (int dd = 0; dd < 32; dd++) {
            float qd = ql[wid][hd * 33 + dd];
            o += qd * c4[dd * 64 + l];
        }
        __syncthreads();
        u16x4 ov;
#pragma unroll
        for (int j = 0; j < 4; j++) ov[j] = f2b(o[j]);
        *reinterpret_cast<u16x4*>(attv + tok * CC + l * 4) = ov;
    }
}

// ---------------- attn_out = LN(rep); y = LN(attn_out + x1), dtype-aware x1 ----------------
__global__ __launch_bounds__(256) void y_kernel(
    const unsigned short* __restrict__ rep, const void* __restrict__ x1,
    const unsigned short* __restrict__ ag, const unsigned short* __restrict__ ab,
    const unsigned short* __restrict__ g2, const unsigned short* __restrict__ b2v,
    unsigned short* __restrict__ yout, const int* __restrict__ flagp)
{
    bool isb = (*flagp != 0);
    int wid = threadIdx.x >> 6, l = threadIdx.x & 63;
    long tok = (long)blockIdx.x * 4 + wid;
    long base = tok * CC + l * 4;
    u16x4 rv = *reinterpret_cast<const u16x4*>(rep + base);
    float f[4];
#pragma unroll
    for (int j = 0; j < 4; j++) f[j] = b2f(rv[j]);
    float mean = wredsum(f[0] + f[1] + f[2] + f[3]) * (1.f / CC);
    float d[4], sq = 0.f;
#pragma unroll
    for (int j = 0; j < 4; j++) { d[j] = f[j] - mean; sq += d[j] * d[j]; }
    float rs = rsqrtf(wredsum(sq) * (1.f / CC) + 1e-5f);
    u16x4 gv = *reinterpret_cast<const u16x4*>(ag + l * 4);
    u16x4 bv = *reinterpret_cast<const u16x4*>(ab + l * 4);
    float xv[4];
    if (isb) {
        u16x4 x4v = *reinterpret_cast<const u16x4*>((const unsigned short*)x1 + base);
#pragma unroll
        for (int j = 0; j < 4; j++) xv[j] = b2f(x4v[j]);
    } else {
        f32x4 x4v = *reinterpret_cast<const f32x4*>((const float*)x1 + base);
#pragma unroll
        for (int j = 0; j < 4; j++) xv[j] = x4v[j];
    }
    float tt[4];
#pragma unroll
    for (int j = 0; j < 4; j++) tt[j] = d[j] * rs * b2f(gv[j]) + b2f(bv[j]) + xv[j];
    float mean2 = wredsum(tt[0] + tt[1] + tt[2] + tt[3]) * (1.f / CC);
    float d2[4], sq2 = 0.f;
#pragma unroll
    for (int j = 0; j < 4; j++) { d2[j] = tt[j] - mean2; sq2 += d2[j] * d2[j]; }
    float rs2 = rsqrtf(wredsum(sq2) * (1.f / CC) + 1e-5f);
    u16x4 gv2 = *reinterpret_cast<const u16x4*>(g2 + l * 4);
    u16x4 bv2 = *reinterpret_cast<const u16x4*>(b2v + l * 4);
    u16x4 o;
#pragma unroll
    for (int j = 0; j < 4; j++) o[j] = f2b(d2[j] * rs2 * b2f(gv2[j]) + b2f(bv2[j]));
    *reinterpret_cast<u16x4*>(yout + base) = o;
}

// ---------------- depthwise 3x3 conv + LN + exact GELU (transposed weights) ----------------
__global__ __launch_bounds__(256) void dw_kernel(
    const unsigned short* __restrict__ h1, const unsigned short* __restrict__ dwt,
    const unsigned short* __restrict__ dwb, const unsigned short* __restrict__ g,
    const unsigned short* __restrict__ bb, unsigned short* __restrict__ ax)
{
    int wid = threadIdx.x >> 6, l = threadIdx.x & 63;
    int pix = blockIdx.x * 4 + wid;
    int b = pix >> 12, rem = pix & 4095, py = rem >> 6, px = rem & 63;
    int c0 = l * 8;
    // coalesced weight loads: 9 taps x u16x8
    u16x8 wv[9];
#pragma unroll
    for (int tap = 0; tap < 9; tap++)
        wv[tap] = *reinterpret_cast<const u16x8*>(dwt + tap * CC2 + c0);
    u16x8 biasv = *reinterpret_cast<const u16x8*>(dwb + c0);
    float acc[8];
#pragma unroll
    for (int j = 0; j < 8; j++) acc[j] = b2f(biasv[j]);
#pragma unroll
    for (int ky = 0; ky < 3; ky++) {
        int ys = py + ky - 1;
        if ((unsigned)ys >= 64u) continue;
#pragma unroll
        for (int kx = 0; kx < 3; kx++) {
            int xs = px + kx - 1;
            if ((unsigned)xs >= 64u) continue;
            u16x8 pv = *reinterpret_cast<const u16x8*>(
                h1 + ((long)(b << 12) + (ys << 6) + xs) * CC2 + c0);
            int tap = ky * 3 + kx;
#pragma unroll
            for (int j = 0; j < 8; j++)
                acc[j] += b2f(pv[j]) * b2f(wv[tap][j]);
        }
    }
    float s = 0.f;
#pragma unroll
    for (int j = 0; j < 8; j++) s += acc[j];
    float mean = wredsum(s) * (1.f / CC2);
    float d[8], sq = 0.f;
#pragma unroll
    for (int j = 0; j < 8; j++) { d[j] = acc[j] - mean; sq += d[j] * d[j]; }
    float rs = rsqrtf(wredsum(sq) * (1.f / CC2) + 1e-5f);
    u16x8 gv = *reinterpret_cast<const u16x8*>(g + c0);
    u16x8 bv = *reinterpret_cast<const u16x8*>(bb + c0);
    u16x8 o;
#pragma unroll
    for (int j = 0; j < 8; j++) {
        float nv = d[j] * rs * b2f(gv[j]) + b2f(bv[j]);
        o[j] = f2b(0.5f * nv * (1.f + erff(nv * 0.70710678118654752f)));
    }
    *reinterpret_cast<u16x8*>(ax + (long)pix * CC2 + c0) = o;
}

// ---------------- final: out = LN(fout + y), dtype-aware output ----------------
__global__ __launch_bounds__(256) void final_kernel(
    const unsigned short* __restrict__ fout, const unsigned short* __restrict__ y,
    const unsigned short* __restrict__ g, const unsigned short* __restrict__ bb,
    void* __restrict__ out, const int* __restrict__ flagp)
{
    bool isb = (*flagp != 0);
    int wid = threadIdx.x >> 6, l = threadIdx.x & 63;
    long tok = (long)blockIdx.x * 4 + wid;
    long base = tok * CC + l * 4;
    u16x4 fv = *reinterpret_cast<const u16x4*>(fout + base);
    u16x4 yv = *reinterpret_cast<const u16x4*>(y + base);
    float f[4];
#pragma unroll
    for (int j = 0; j < 4; j++) f[j] = b2f(fv[j]) + b2f(yv[j]);
    float mean = wredsum(f[0] + f[1] + f[2] + f[3]) * (1.f / CC);
    float d[4], sq = 0.f;
#pragma unroll
    for (int j = 0; j < 4; j++) { d[j] = f[j] - mean; sq += d[j] * d[j]; }
    float rs = rsqrtf(wredsum(sq) * (1.f / CC) + 1e-5f);
    u16x4 gv = *reinterpret_cast<const u16x4*>(g + l * 4);
    u16x4 bv = *reinterpret_cast<const u16x4*>(bb + l * 4);
    float r[4];
#pragma unroll
    for (int j = 0; j < 4; j++) r[j] = d[j] * rs * b2f(gv[j]) + b2f(bv[j]);
    if (isb) {
        u16x4 o;
#pragma unroll
        for (int j = 0; j < 4; j++) o[j] = f2b(r[j]);
        *reinterpret_cast<u16x4*>((unsigned short*)out + base) = o;
    } else {
        f32x4 o;
#pragma unroll
        for (int j = 0; j < 4; j++) o[j] = r[j];
        *reinterpret_cast<f32x4*>((float*)out + base) = o;
    }
}

extern "C" void kernel_launch(void* const* d_in, const int* in_sizes, int n_in,
                              void* d_out, int out_size, void* d_ws, size_t ws_size,
                              hipStream_t stream)
{
    char* w = (char*)d_ws;
    const size_t S1B = (size_t)BTOK * CC * 2;   // 16.78 MB
    const size_t STATSB = (size_t)(2 * NBATCH * CC + NBATCH * 8 * 32 * 32) * 4;
    const size_t PARAMS_ELEMS = 402688 + 4608;  // + transposed dw weights
    const size_t need = 6 * S1B + STATSB + 64 + PARAMS_ELEMS * 2;
    if (ws_size < need) return;

    unsigned short* ln12 = (unsigned short*)w;
    unsigned short* n12  = (unsigned short*)(w + 2 * S1B);
    unsigned short* nn1  = n12;
    unsigned short* nn2  = n12 + (size_t)BTOK * CC;
    unsigned short* attv = ln12;
    unsigned short* rep  = ln12 + (size_t)BTOK * CC;
    unsigned short* ybuf = nn1;
    unsigned short* fout = nn2;
    unsigned short* h1   = ln12;
    unsigned short* axb  = (unsigned short*)(w + 4 * S1B);
    // transient scratch inside the (not-yet-used) axb region:
    float* pm   = (float*)(w + 4 * S1B);                 // 512 KB
    float* ps   = (float*)(w + 4 * S1B + (512 << 10));   // 512 KB
    float* pctx = (float*)(w + 4 * S1B + (2048 << 10));  // 4 MB
    float* kmax = (float*)(w + 6 * S1B);
    float* ksum = kmax + NBATCH * CC;
    float* ctxb = ksum + NBATCH * CC;
    int*   flag = (int*)(w + 6 * S1B + STATSB);
    unsigned short* pb = (unsigned short*)(w + 6 * S1B + STATSB + 64);

    // bf16 param block offsets
    unsigned short* n1g  = pb + 0;
    unsigned short* n1b  = pb + 256;
    unsigned short* linw = pb + 512;
    unsigned short* linb = pb + 66048;
    unsigned short* repw = pb + 66304;
    unsigned short* repb = pb + 131840;
    unsigned short* ang  = pb + 132096;
    unsigned short* anb  = pb + 132352;
    unsigned short* g2   = pb + 132608;
    unsigned short* b2v  = pb + 132864;
    unsigned short* fc1w = pb + 133120;
    unsigned short* fc1b = pb + 264192;
    unsigned short* dwb  = pb + 269312;
    unsigned short* fn1g = pb + 269824;
    unsigned short* fn1b = pb + 270336;
    unsigned short* fc2w = pb + 270848;
    unsigned short* fc2b = pb + 401920;
    unsigned short* fn3g = pb + 402176;
    unsigned short* fn3b = pb + 402432;
    unsigned short* dwt  = pb + 402688;   // [9][512] transposed dw weights

    probe_kernel<<<1, 256, 0, stream>>>((const unsigned short*)d_in[0], flag);
    cvt_params_kernel<<<512, 256, 0, stream>>>(flag,
        d_in[2], d_in[3], d_in[4], d_in[5], d_in[6], d_in[7], d_in[8], d_in[9],
        d_in[10], d_in[11], d_in[12], d_in[13], d_in[14], d_in[15], d_in[16],
        d_in[17], d_in[18], d_in[19], d_in[20], d_in[21], pb);
    dw_transpose_kernel<<<1, 256, 0, stream>>>(d_in[14], dwt, flag);
    ln_dual_kernel<<<2 * BTOK / 4, 256, 0, stream>>>(d_in[0], d_in[1], n1g, n1b, ln12, flag);
    gemm_bt_kernel<256><<<(2 * BTOK / 32) * (CC / 32) / 4, 256, 0, stream>>>(
        ln12, linw, linb, n12, 2 * BTOK, CC);
    colstats1_kernel<<<NBATCH * 64, 256, 0, stream>>>(nn2, pm, ps);
    colstats2_kernel<<<NBATCH, 256, 0, stream>>>(pm, ps, kmax, ksum);
    ctx_part_kernel<<<NBATCH * 8 * 16, 256, 0, stream>>>(nn2, kmax, ksum, pctx);
    ctx_reduce_kernel<<<256, 256, 0, stream>>>(pctx, ctxb);
    att_kernel<<<NBATCH * 64, 256, 0, stream>>>(nn1, ctxb, attv);
    gemm_bt_kernel<256><<<(BTOK / 32) * (CC / 32) / 4, 256, 0, stream>>>(
        attv, repw, repb, rep, BTOK, CC);
    y_kernel<<<BTOK / 4, 256, 0, stream>>>(rep, d_in[0], ang, anb, g2, b2v, ybuf, flag);
    gemm_bt_kernel<256><<<(BTOK / 32) * (CC2 / 32) / 4, 256, 0, stream>>>(
        ybuf, fc1w, fc1b, h1, BTOK, CC2);
    dw_kernel<<<BTOK / 4, 256, 0, stream>>>(h1, dwt, dwb, fn1g, fn1b, axb);
    gemm_bt_kernel<512><<<(BTOK / 32) * (CC / 32) / 4, 256, 0, stream>>>(
        axb, fc2w, fc2b, fout, BTOK, CC);
    final_kernel<<<BTOK / 4, 256, 0, stream>>>(fout, ybuf, fn3g, fn3b, d_out, flag);
}

// Round 6
// 242.544 us; speedup vs baseline: 2.9835x; 1.6096x over previous
//
#include <hip/hip_runtime.h>

#define BTOK 32768   // B*H*W tokens
#define CC 256
#define CC2 512
#define NBATCH 8

typedef __bf16 bf16x8 __attribute__((ext_vector_type(8)));
typedef float f32x4 __attribute__((ext_vector_type(4)));
typedef unsigned short u16x8 __attribute__((ext_vector_type(8)));
typedef unsigned short u16x4 __attribute__((ext_vector_type(4)));

__device__ __forceinline__ float b2f(unsigned short u) {
    return __uint_as_float(((unsigned)u) << 16);
}
__device__ __forceinline__ unsigned short f2b(float f) {
    unsigned x = __float_as_uint(f);
    return (unsigned short)((x + 0x7fffu + ((x >> 16) & 1u)) >> 16);
}
__device__ __forceinline__ float wredsum(float v) {
#pragma unroll
    for (int m = 1; m < 64; m <<= 1) v += __shfl_xor(v, m);
    return v;
}

typedef __attribute__((address_space(3))) unsigned int lds_u32;
typedef const __attribute__((address_space(1))) unsigned int glb_u32;
__device__ __forceinline__ void gload_lds16(const unsigned short* g, unsigned short* l) {
    __builtin_amdgcn_global_load_lds((glb_u32*)g, (lds_u32*)l, 16, 0, 0);
}

// ---------------- dtype probe: 1 = bf16 inputs, 0 = f32 inputs ----------------
__global__ __launch_bounds__(256) void probe_kernel(
    const unsigned short* __restrict__ x, int* __restrict__ flag)
{
    int t = threadIdx.x;
    int c = 0;
    for (int i = t; i < 1024; i += 256) {
        unsigned e = (x[i] >> 7) & 0xFFu;
        c += (e >= 110u && e <= 135u) ? 1 : 0;
    }
#pragma unroll
    for (int m = 1; m < 64; m <<= 1) c += __shfl_xor(c, m);
    __shared__ int acc[4];
    if ((t & 63) == 0) acc[t >> 6] = c;
    __syncthreads();
    if (t == 0) *flag = ((acc[0] + acc[1] + acc[2] + acc[3]) >= 896) ? 1 : 0;
}

// ---------------- convert all params to bf16 in ws ----------------
__global__ __launch_bounds__(256) void cvt_params_kernel(
    const int* __restrict__ flagp,
    const void* p0, const void* p1, const void* p2, const void* p3, const void* p4,
    const void* p5, const void* p6, const void* p7, const void* p8, const void* p9,
    const void* p10, const void* p11, const void* p12, const void* p13, const void* p14,
    const void* p15, const void* p16, const void* p17, const void* p18, const void* p19,
    unsigned short* __restrict__ dst)
{
    bool isb = (*flagp != 0);
    long g = (long)blockIdx.x * 256 + threadIdx.x;
    long str = (long)gridDim.x * 256;
#define CVT(src, off, n)                                                        \
    for (long i = g; i < (long)(n); i += str)                                   \
        dst[(off) + i] = isb ? ((const unsigned short*)(src))[i]                \
                             : f2b(((const float*)(src))[i]);
    CVT(p0, 0, 256)          // n1g
    CVT(p1, 256, 256)        // n1b
    CVT(p2, 512, 65536)      // linw
    CVT(p3, 66048, 256)      // linb
    CVT(p4, 66304, 65536)    // repw
    CVT(p5, 131840, 256)     // repb
    CVT(p6, 132096, 256)     // ang
    CVT(p7, 132352, 256)     // anb
    CVT(p8, 132608, 256)     // g2
    CVT(p9, 132864, 256)     // b2v
    CVT(p10, 133120, 131072) // fc1w
    CVT(p11, 264192, 512)    // fc1b
    CVT(p12, 264704, 4608)   // dww
    CVT(p13, 269312, 512)    // dwb
    CVT(p14, 269824, 512)    // fn1g
    CVT(p15, 270336, 512)    // fn1b
    CVT(p16, 270848, 131072) // fc2w
    CVT(p17, 401920, 256)    // fc2b
    CVT(p18, 402176, 256)    // fn3g
    CVT(p19, 402432, 256)    // fn3b
#undef CVT
}

// ---------------- transpose dw weights: dwt[tap][c] = dww[c][tap] ----------------
__global__ __launch_bounds__(256) void dw_transpose_kernel(
    const void* __restrict__ src, unsigned short* __restrict__ dwt,
    const int* __restrict__ flagp)
{
    bool isb = (*flagp != 0);
    for (int i = threadIdx.x; i < 4608; i += 256) {
        int tap = i >> 9, c = i & 511;
        dwt[i] = isb ? ((const unsigned short*)src)[c * 9 + tap]
                     : f2b(((const float*)src)[c * 9 + tap]);
    }
}

// ---------------- LN of x1 and x2 (shared norm1 params), dtype-aware ----------------
__global__ __launch_bounds__(256) void ln_dual_kernel(
    const void* __restrict__ x1, const void* __restrict__ x2,
    const unsigned short* __restrict__ g, const unsigned short* __restrict__ b,
    unsigned short* __restrict__ out, const int* __restrict__ flagp)
{
    bool isb = (*flagp != 0);
    int wid = threadIdx.x >> 6, l = threadIdx.x & 63;
    long row = (long)blockIdx.x * 4 + wid;   // 0 .. 2*BTOK-1
    const void* xsel = (row < BTOK) ? x1 : x2;
    long r = (row < BTOK) ? row : (row - BTOK);
    float f[4];
    if (isb) {
        u16x4 v = *reinterpret_cast<const u16x4*>((const unsigned short*)xsel + r * CC + l * 4);
#pragma unroll
        for (int j = 0; j < 4; j++) f[j] = b2f(v[j]);
    } else {
        f32x4 v = *reinterpret_cast<const f32x4*>((const float*)xsel + r * CC + l * 4);
#pragma unroll
        for (int j = 0; j < 4; j++) f[j] = v[j];
    }
    float mean = wredsum(f[0] + f[1] + f[2] + f[3]) * (1.f / CC);
    float d[4], sq = 0.f;
#pragma unroll
    for (int j = 0; j < 4; j++) { d[j] = f[j] - mean; sq += d[j] * d[j]; }
    float rs = rsqrtf(wredsum(sq) * (1.f / CC) + 1e-5f);
    u16x4 gv = *reinterpret_cast<const u16x4*>(g + l * 4);
    u16x4 bv = *reinterpret_cast<const u16x4*>(b + l * 4);
    u16x4 o;
#pragma unroll
    for (int j = 0; j < 4; j++) o[j] = f2b(d[j] * rs * b2f(gv[j]) + b2f(bv[j]));
    *reinterpret_cast<u16x4*>(out + row * CC + l * 4) = o;
}

// ---------------- GEMM (m97 structure): 128x128 tile, BK=32, global_load_lds ----------------
// out[t][o] = sum_k A[t][k]*W[o][k] + bias[o];  A: T x K, W: O x K (both K-major bf16)
template<int K>
__global__ __launch_bounds__(256) void gemm_lds_kernel(
    const unsigned short* __restrict__ A, const unsigned short* __restrict__ Wt,
    const unsigned short* __restrict__ bias, unsigned short* __restrict__ out,
    int O, int nwg)
{
    __shared__ unsigned short Asm[128 * 32];
    __shared__ unsigned short Bsm[128 * 32];
    int t = threadIdx.x;
    int l = t & 63, w = t >> 6;
    // bijective XCD swizzle (nwg % 8 == 0 for all our grids)
    int bid = blockIdx.x;
    int cpx = nwg >> 3;
    int wg = (bid & 7) * cpx + (bid >> 3);
    int ntn = O >> 7;
    long tm = (long)(wg / ntn) << 7;
    int tn = (wg % ntn) << 7;
    int wr = (w >> 1) << 6;           // wave row offset in tile: 0/64
    int wc = (w & 1) << 6;            // wave col offset in tile: 0/64

    // staging: thread t covers LDS 16B slot t (i=0) and 256+t (i=1)
    int rloc = t >> 2;                // row within 64-row group
    int q = (t & 3) ^ ((t >> 3) & 3); // k-group at inverse-swizzled global source
    const unsigned short* ga0 = A + (tm + rloc) * K + q * 8;
    const unsigned short* ga1 = A + (tm + 64 + rloc) * K + q * 8;
    const unsigned short* gb0 = Wt + (long)(tn + rloc) * K + q * 8;
    const unsigned short* gb1 = Wt + (long)(tn + 64 + rloc) * K + q * 8;
    unsigned short* la0 = &Asm[w * 512];
    unsigned short* la1 = &Asm[2048 + w * 512];
    unsigned short* lb0 = &Bsm[w * 512];
    unsigned short* lb1 = &Bsm[2048 + w * 512];

    // swizzled fragment read offsets: row r, slot s = (l>>4) ^ ((r>>1)&3)
    int rr = l & 15;
    int sA = ((l >> 4) ^ ((rr >> 1) & 3)) << 3;   // halfword offset of 16B slot
    int aoff[4], boff[4];
#pragma unroll
    for (int m = 0; m < 4; m++) aoff[m] = (wr + m * 16 + rr) * 32 + sA;
#pragma unroll
    for (int n = 0; n < 4; n++) boff[n] = (wc + n * 16 + rr) * 32 + sA;

    f32x4 acc[4][4];
#pragma unroll
    for (int m = 0; m < 4; m++)
#pragma unroll
        for (int n = 0; n < 4; n++) acc[m][n] = {0.f, 0.f, 0.f, 0.f};

    for (int kt = 0; kt < K / 32; kt++) {
        int k0 = kt * 32;
        gload_lds16(ga0 + k0, la0);
        gload_lds16(ga1 + k0, la1);
        gload_lds16(gb0 + k0, lb0);
        gload_lds16(gb1 + k0, lb1);
        __syncthreads();
        bf16x8 af[4], bfr[4];
#pragma unroll
        for (int m = 0; m < 4; m++) af[m] = *reinterpret_cast<const bf16x8*>(&Asm[aoff[m]]);
#pragma unroll
        for (int n = 0; n < 4; n++) bfr[n] = *reinterpret_cast<const bf16x8*>(&Bsm[boff[n]]);
#pragma unroll
        for (int m = 0; m < 4; m++)
#pragma unroll
            for (int n = 0; n < 4; n++)
                acc[m][n] = __builtin_amdgcn_mfma_f32_16x16x32_bf16(af[m], bfr[n], acc[m][n], 0, 0, 0);
        __syncthreads();
    }

    int orow = (l >> 4) << 2;
    int ocol = l & 15;
    float bi[4];
#pragma unroll
    for (int n = 0; n < 4; n++) bi[n] = b2f(bias[tn + wc + n * 16 + ocol]);
#pragma unroll
    for (int m = 0; m < 4; m++) {
#pragma unroll
        for (int n = 0; n < 4; n++) {
#pragma unroll
            for (int j = 0; j < 4; j++) {
                out[(tm + wr + m * 16 + orow + j) * O + tn + wc + n * 16 + ocol] =
                    f2b(acc[m][n][j] + bi[n]);
            }
        }
    }
}

// ---------------- colstats stage 1: per-slab online (max,sum) ----------------
__global__ __launch_bounds__(256) void colstats1_kernel(
    const unsigned short* __restrict__ n2, float* __restrict__ pm, float* __restrict__ ps)
{
    int b = blockIdx.x >> 6, slab = blockIdx.x & 63;
    int t = threadIdx.x;
    int c0 = (t & 63) << 2;
    int r = t >> 6;
    const unsigned short* base = n2 + ((long)b * 4096 + slab * 64 + r) * CC + c0;
    float m[4] = {-3.0e38f, -3.0e38f, -3.0e38f, -3.0e38f};
    float s[4] = {0.f, 0.f, 0.f, 0.f};
#pragma unroll 4
    for (int i = 0; i < 16; i++) {
        u16x4 v = *reinterpret_cast<const u16x4*>(base + (long)i * 4 * CC);
#pragma unroll
        for (int j = 0; j < 4; j++) {
            float x = b2f(v[j]);
            if (x > m[j]) { s[j] = s[j] * __expf(m[j] - x) + 1.f; m[j] = x; }
            else s[j] += __expf(x - m[j]);
        }
    }
    __shared__ float lm[4][256], lsb[4][256];
#pragma unroll
    for (int j = 0; j < 4; j++) { lm[r][c0 + j] = m[j]; lsb[r][c0 + j] = s[j]; }
    __syncthreads();
    if (r == 0) {
#pragma unroll
        for (int w = 1; w < 4; w++) {
#pragma unroll
            for (int j = 0; j < 4; j++) {
                float mi = lm[w][c0 + j], si = lsb[w][c0 + j];
                if (mi > m[j]) { s[j] = s[j] * __expf(m[j] - mi) + si; m[j] = mi; }
                else s[j] += si * __expf(mi - m[j]);
            }
        }
        long o = ((long)(b * 64 + slab)) * 256 + c0;
#pragma unroll
        for (int j = 0; j < 4; j++) { pm[o + j] = m[j]; ps[o + j] = s[j]; }
    }
}

// ---------------- colstats stage 2: merge 64 slabs ----------------
__global__ __launch_bounds__(256) void colstats2_kernel(
    const float* __restrict__ pm, const float* __restrict__ ps,
    float* __restrict__ kmax, float* __restrict__ ksum)
{
    int b = blockIdx.x, c = threadIdx.x;
    float M = -3.0e38f, S = 0.f;
    for (int s = 0; s < 64; s++) {
        long o = ((long)(b * 64 + s)) * 256 + c;
        float mi = pm[o], si = ps[o];
        if (mi > M) { S = S * __expf(M - mi) + si; M = mi; }
        else S += si * __expf(mi - M);
    }
    kmax[b * CC + c] = M;
    ksum[b * CC + c] = S;
}

// ---------------- ctx partial: slab of 256 tokens per block ----------------
__global__ __launch_bounds__(256) void ctx_part_kernel(
    const unsigned short* __restrict__ n2, const float* __restrict__ kmax,
    const float* __restrict__ ksum, float* __restrict__ pctx)
{
    int blk = blockIdx.x;
    int b = blk >> 7, hd = (blk >> 4) & 7, slab = blk & 15;
    int t = threadIdx.x;
    __shared__ float ld[32][33], eld[32][33];
    int d = t >> 3;
    int v0 = (t & 7) << 2;
    int ln_ = t >> 3;
    int lc = (t & 7) << 2;
    float kmx4[4], kin4[4];
#pragma unroll
    for (int j = 0; j < 4; j++) {
        kmx4[j] = kmax[b * CC + hd * 32 + lc + j];
        kin4[j] = 1.f / ksum[b * CC + hd * 32 + lc + j];
    }
    f32x4 acc = {0.f, 0.f, 0.f, 0.f};
    const unsigned short* base = n2 + ((long)b * 4096 + slab * 256) * CC + hd * 32;
    for (int n0 = 0; n0 < 256; n0 += 32) {
        u16x4 rv = *reinterpret_cast<const u16x4*>(base + (long)(n0 + ln_) * CC + lc);
#pragma unroll
        for (int j = 0; j < 4; j++) {
            float x = b2f(rv[j]);
            ld[ln_][lc + j] = x;
            eld[ln_][lc + j] = __expf(x - kmx4[j]) * kin4[j];
        }
        __syncthreads();
#pragma unroll 4
        for (int nn = 0; nn < 32; nn++) {
            float e = eld[nn][d];
#pragma unroll
            for (int j = 0; j < 4; j++) acc[j] += e * ld[nn][v0 + j];
        }
        __syncthreads();
    }
    long o = ((long)slab * NBATCH * 8 + (long)b * 8 + hd) * 1024 + (long)d * 32 + v0;
#pragma unroll
    for (int j = 0; j < 4; j++) pctx[o + j] = acc[j];
}

// ---------------- ctx reduce: sum 16 slab partials ----------------
__global__ __launch_bounds__(256) void ctx_reduce_kernel(
    const float* __restrict__ pctx, float* __restrict__ ctx)
{
    long i = (long)blockIdx.x * 256 + threadIdx.x;
    float s = 0.f;
#pragma unroll
    for (int sl = 0; sl < 16; sl++) s += pctx[(long)sl * 65536 + i];
    ctx[i] = s;
}

// ---------------- q-softmax + att = ctx^T q, per token ----------------
__global__ __launch_bounds__(256) void att_kernel(
    const unsigned short* __restrict__ n1, const float* __restrict__ ctx,
    unsigned short* __restrict__ attv)
{
    __shared__ float cl[32 * 256];
    __shared__ float ql[4][264];
    int b = blockIdx.x >> 6, grp = blockIdx.x & 63;
    int t = threadIdx.x, wid = t >> 6, l = t & 63;
    const float* cb = ctx + (long)b * 8192;
    for (int i = 0; i < 32; i++) {
        int gidx = t + (i << 8);
        int hd_ = gidx >> 10, dd = (gidx >> 5) & 31, vv = gidx & 31;
        cl[dd * 256 + hd_ * 32 + vv] = cb[gidx];
    }
    __syncthreads();
    int hd = l >> 3;
    long tokbase = (long)b * 4096 + grp * 64 + wid * 16;
    const f32x4* c4 = reinterpret_cast<const f32x4*>(cl);
    for (int it = 0; it < 16; it++) {
        long tok = tokbase + it;
        u16x4 rv = *reinterpret_cast<const u16x4*>(n1 + tok * CC + l * 4);
        float x[4];
#pragma unroll
        for (int j = 0; j < 4; j++) x[j] = b2f(rv[j]);
        float mx = fmaxf(fmaxf(x[0], x[1]), fmaxf(x[2], x[3]));
        mx = fmaxf(mx, __shfl_xor(mx, 1));
        mx = fmaxf(mx, __shfl_xor(mx, 2));
        mx = fmaxf(mx, __shfl_xor(mx, 4));
        float e[4], s = 0.f;
#pragma unroll
        for (int j = 0; j < 4; j++) { e[j] = __expf(x[j] - mx); s += e[j]; }
        s += __shfl_xor(s, 1);
        s += __shfl_xor(s, 2);
        s += __shfl_xor(s, 4);
        float inv = 1.f / s;
#pragma unroll
        for (int j = 0; j < 4; j++) ql[wid][hd * 33 + ((l & 7) << 2) + j] = e[j] * inv;
        __syncthreads();
        f32x4 o = {0.f, 0.f, 0.f, 0.f};
#pragma unroll 8
        for (int dd = 0; dd < 32; dd++) {
            float qd = ql[wid][hd * 33 + dd];
            o += qd * c4[dd * 64 + l];
        }
        __syncthreads();
        u16x4 ov;
#pragma unroll
        for (int j = 0; j < 4; j++) ov[j] = f2b(o[j]);
        *reinterpret_cast<u16x4*>(attv + tok * CC + l * 4) = ov;
    }
}

// ---------------- attn_out = LN(rep); y = LN(attn_out + x1), dtype-aware x1 ----------------
__global__ __launch_bounds__(256) void y_kernel(
    const unsigned short* __restrict__ rep, const void* __restrict__ x1,
    const unsigned short* __restrict__ ag, const unsigned short* __restrict__ ab,
    const unsigned short* __restrict__ g2, const unsigned short* __restrict__ b2v,
    unsigned short* __restrict__ yout, const int* __restrict__ flagp)
{
    bool isb = (*flagp != 0);
    int wid = threadIdx.x >> 6, l = threadIdx.x & 63;
    long tok = (long)blockIdx.x * 4 + wid;
    long base = tok * CC + l * 4;
    u16x4 rv = *reinterpret_cast<const u16x4*>(rep + base);
    float f[4];
#pragma unroll
    for (int j = 0; j < 4; j++) f[j] = b2f(rv[j]);
    float mean = wredsum(f[0] + f[1] + f[2] + f[3]) * (1.f / CC);
    float d[4], sq = 0.f;
#pragma unroll
    for (int j = 0; j < 4; j++) { d[j] = f[j] - mean; sq += d[j] * d[j]; }
    float rs = rsqrtf(wredsum(sq) * (1.f / CC) + 1e-5f);
    u16x4 gv = *reinterpret_cast<const u16x4*>(ag + l * 4);
    u16x4 bv = *reinterpret_cast<const u16x4*>(ab + l * 4);
    float xv[4];
    if (isb) {
        u16x4 x4v = *reinterpret_cast<const u16x4*>((const unsigned short*)x1 + base);
#pragma unroll
        for (int j = 0; j < 4; j++) xv[j] = b2f(x4v[j]);
    } else {
        f32x4 x4v = *reinterpret_cast<const f32x4*>((const float*)x1 + base);
#pragma unroll
        for (int j = 0; j < 4; j++) xv[j] = x4v[j];
    }
    float tt[4];
#pragma unroll
    for (int j = 0; j < 4; j++) tt[j] = d[j] * rs * b2f(gv[j]) + b2f(bv[j]) + xv[j];
    float mean2 = wredsum(tt[0] + tt[1] + tt[2] + tt[3]) * (1.f / CC);
    float d2[4], sq2 = 0.f;
#pragma unroll
    for (int j = 0; j < 4; j++) { d2[j] = tt[j] - mean2; sq2 += d2[j] * d2[j]; }
    float rs2 = rsqrtf(wredsum(sq2) * (1.f / CC) + 1e-5f);
    u16x4 gv2 = *reinterpret_cast<const u16x4*>(g2 + l * 4);
    u16x4 bv2 = *reinterpret_cast<const u16x4*>(b2v + l * 4);
    u16x4 o;
#pragma unroll
    for (int j = 0; j < 4; j++) o[j] = f2b(d2[j] * rs2 * b2f(gv2[j]) + b2f(bv2[j]));
    *reinterpret_cast<u16x4*>(yout + base) = o;
}

// ---------------- depthwise 3x3 conv + LN + exact GELU (transposed weights) ----------------
__global__ __launch_bounds__(256) void dw_kernel(
    const unsigned short* __restrict__ h1, const unsigned short* __restrict__ dwt,
    const unsigned short* __restrict__ dwb, const unsigned short* __restrict__ g,
    const unsigned short* __restrict__ bb, unsigned short* __restrict__ ax)
{
    int wid = threadIdx.x >> 6, l = threadIdx.x & 63;
    int pix = blockIdx.x * 4 + wid;
    int b = pix >> 12, rem = pix & 4095, py = rem >> 6, px = rem & 63;
    int c0 = l * 8;
    u16x8 wv[9];
#pragma unroll
    for (int tap = 0; tap < 9; tap++)
        wv[tap] = *reinterpret_cast<const u16x8*>(dwt + tap * CC2 + c0);
    u16x8 biasv = *reinterpret_cast<const u16x8*>(dwb + c0);
    float acc[8];
#pragma unroll
    for (int j = 0; j < 8; j++) acc[j] = b2f(biasv[j]);
#pragma unroll
    for (int ky = 0; ky < 3; ky++) {
        int ys = py + ky - 1;
        if ((unsigned)ys >= 64u) continue;
#pragma unroll
        for (int kx = 0; kx < 3; kx++) {
            int xs = px + kx - 1;
            if ((unsigned)xs >= 64u) continue;
            u16x8 pv = *reinterpret_cast<const u16x8*>(
                h1 + ((long)(b << 12) + (ys << 6) + xs) * CC2 + c0);
            int tap = ky * 3 + kx;
#pragma unroll
            for (int j = 0; j < 8; j++)
                acc[j] += b2f(pv[j]) * b2f(wv[tap][j]);
        }
    }
    float s = 0.f;
#pragma unroll
    for (int j = 0; j < 8; j++) s += acc[j];
    float mean = wredsum(s) * (1.f / CC2);
    float d[8], sq = 0.f;
#pragma unroll
    for (int j = 0; j < 8; j++) { d[j] = acc[j] - mean; sq += d[j] * d[j]; }
    float rs = rsqrtf(wredsum(sq) * (1.f / CC2) + 1e-5f);
    u16x8 gv = *reinterpret_cast<const u16x8*>(g + c0);
    u16x8 bv = *reinterpret_cast<const u16x8*>(bb + c0);
    u16x8 o;
#pragma unroll
    for (int j = 0; j < 8; j++) {
        float nv = d[j] * rs * b2f(gv[j]) + b2f(bv[j]);
        o[j] = f2b(0.5f * nv * (1.f + erff(nv * 0.70710678118654752f)));
    }
    *reinterpret_cast<u16x8*>(ax + (long)pix * CC2 + c0) = o;
}

// ---------------- final: out = LN(fout + y), dtype-aware output ----------------
__global__ __launch_bounds__(256) void final_kernel(
    const unsigned short* __restrict__ fout, const unsigned short* __restrict__ y,
    const unsigned short* __restrict__ g, const unsigned short* __restrict__ bb,
    void* __restrict__ out, const int* __restrict__ flagp)
{
    bool isb = (*flagp != 0);
    int wid = threadIdx.x >> 6, l = threadIdx.x & 63;
    long tok = (long)blockIdx.x * 4 + wid;
    long base = tok * CC + l * 4;
    u16x4 fv = *reinterpret_cast<const u16x4*>(fout + base);
    u16x4 yv = *reinterpret_cast<const u16x4*>(y + base);
    float f[4];
#pragma unroll
    for (int j = 0; j < 4; j++) f[j] = b2f(fv[j]) + b2f(yv[j]);
    float mean = wredsum(f[0] + f[1] + f[2] + f[3]) * (1.f / CC);
    float d[4], sq = 0.f;
#pragma unroll
    for (int j = 0; j < 4; j++) { d[j] = f[j] - mean; sq += d[j] * d[j]; }
    float rs = rsqrtf(wredsum(sq) * (1.f / CC) + 1e-5f);
    u16x4 gv = *reinterpret_cast<const u16x4*>(g + l * 4);
    u16x4 bv = *reinterpret_cast<const u16x4*>(bb + l * 4);
    float r[4];
#pragma unroll
    for (int j = 0; j < 4; j++) r[j] = d[j] * rs * b2f(gv[j]) + b2f(bv[j]);
    if (isb) {
        u16x4 o;
#pragma unroll
        for (int j = 0; j < 4; j++) o[j] = f2b(r[j]);
        *reinterpret_cast<u16x4*>((unsigned short*)out + base) = o;
    } else {
        f32x4 o;
#pragma unroll
        for (int j = 0; j < 4; j++) o[j] = r[j];
        *reinterpret_cast<f32x4*>((float*)out + base) = o;
    }
}

extern "C" void kernel_launch(void* const* d_in, const int* in_sizes, int n_in,
                              void* d_out, int out_size, void* d_ws, size_t ws_size,
                              hipStream_t stream)
{
    char* w = (char*)d_ws;
    const size_t S1B = (size_t)BTOK * CC * 2;   // 16.78 MB
    const size_t STATSB = (size_t)(2 * NBATCH * CC + NBATCH * 8 * 32 * 32) * 4;
    const size_t PARAMS_ELEMS = 402688 + 4608;
    const size_t need = 6 * S1B + STATSB + 64 + PARAMS_ELEMS * 2;
    if (ws_size < need) return;

    unsigned short* ln12 = (unsigned short*)w;
    unsigned short* n12  = (unsigned short*)(w + 2 * S1B);
    unsigned short* nn1  = n12;
    unsigned short* nn2  = n12 + (size_t)BTOK * CC;
    unsigned short* attv = ln12;
    unsigned short* rep  = ln12 + (size_t)BTOK * CC;
    unsigned short* ybuf = nn1;
    unsigned short* fout = nn2;
    unsigned short* h1   = ln12;
    unsigned short* axb  = (unsigned short*)(w + 4 * S1B);
    float* pm   = (float*)(w + 4 * S1B);
    float* ps   = (float*)(w + 4 * S1B + (512 << 10));
    float* pctx = (float*)(w + 4 * S1B + (2048 << 10));
    float* kmax = (float*)(w + 6 * S1B);
    float* ksum = kmax + NBATCH * CC;
    float* ctxb = ksum + NBATCH * CC;
    int*   flag = (int*)(w + 6 * S1B + STATSB);
    unsigned short* pb = (unsigned short*)(w + 6 * S1B + STATSB + 64);

    unsigned short* n1g  = pb + 0;
    unsigned short* n1b  = pb + 256;
    unsigned short* linw = pb + 512;
    unsigned short* linb = pb + 66048;
    unsigned short* repw = pb + 66304;
    unsigned short* repb = pb + 131840;
    unsigned short* ang  = pb + 132096;
    unsigned short* anb  = pb + 132352;
    unsigned short* g2   = pb + 132608;
    unsigned short* b2v  = pb + 132864;
    unsigned short* fc1w = pb + 133120;
    unsigned short* fc1b = pb + 264192;
    unsigned short* dwb  = pb + 269312;
    unsigned short* fn1g = pb + 269824;
    unsigned short* fn1b = pb + 270336;
    unsigned short* fc2w = pb + 270848;
    unsigned short* fc2b = pb + 401920;
    unsigned short* fn3g = pb + 402176;
    unsigned short* fn3b = pb + 402432;
    unsigned short* dwt  = pb + 402688;

    probe_kernel<<<1, 256, 0, stream>>>((const unsigned short*)d_in[0], flag);
    cvt_params_kernel<<<512, 256, 0, stream>>>(flag,
        d_in[2], d_in[3], d_in[4], d_in[5], d_in[6], d_in[7], d_in[8], d_in[9],
        d_in[10], d_in[11], d_in[12], d_in[13], d_in[14], d_in[15], d_in[16],
        d_in[17], d_in[18], d_in[19], d_in[20], d_in[21], pb);
    dw_transpose_kernel<<<1, 256, 0, stream>>>(d_in[14], dwt, flag);
    ln_dual_kernel<<<2 * BTOK / 4, 256, 0, stream>>>(d_in[0], d_in[1], n1g, n1b, ln12, flag);
    {   // lin: T = 2*BTOK, O = 256
        int nwg = (2 * BTOK / 128) * (CC / 128);   // 1024
        gemm_lds_kernel<256><<<nwg, 256, 0, stream>>>(ln12, linw, linb, n12, CC, nwg);
    }
    colstats1_kernel<<<NBATCH * 64, 256, 0, stream>>>(nn2, pm, ps);
    colstats2_kernel<<<NBATCH, 256, 0, stream>>>(pm, ps, kmax, ksum);
    ctx_part_kernel<<<NBATCH * 8 * 16, 256, 0, stream>>>(nn2, kmax, ksum, pctx);
    ctx_reduce_kernel<<<256, 256, 0, stream>>>(pctx, ctxb);
    att_kernel<<<NBATCH * 64, 256, 0, stream>>>(nn1, ctxb, attv);
    {   // reproj: T = BTOK, O = 256
        int nwg = (BTOK / 128) * (CC / 128);       // 512
        gemm_lds_kernel<256><<<nwg, 256, 0, stream>>>(attv, repw, repb, rep, CC, nwg);
    }
    y_kernel<<<BTOK / 4, 256, 0, stream>>>(rep, d_in[0], ang, anb, g2, b2v, ybuf, flag);
    {   // fc1: T = BTOK, O = 512
        int nwg = (BTOK / 128) * (CC2 / 128);      // 1024
        gemm_lds_kernel<256><<<nwg, 256, 0, stream>>>(ybuf, fc1w, fc1b, h1, CC2, nwg);
    }
    dw_kernel<<<BTOK / 4, 256, 0, stream>>>(h1, dwt, dwb, fn1g, fn1b, axb);
    {   // fc2: T = BTOK, O = 256, K = 512
        int nwg = (BTOK / 128) * (CC / 128);       // 512
        gemm_lds_kernel<512><<<nwg, 256, 0, stream>>>(axb, fc2w, fc2b, fout, CC, nwg);
    }
    final_kernel<<<BTOK / 4, 256, 0, stream>>>(fout, ybuf, fn3g, fn3b, d_out, flag);
}